// Round 3
// baseline (4024.034 us; speedup 1.0000x reference)
//
#include <hip/hip_runtime.h>
#include <math.h>

// ---------------------------------------------------------------------------
// CapsNet forward, fp32 everywhere (no fp32 MFMA on CDNA4 -> vector ALU).
// R3: k_conv2 v3 — register budget pinned (amdgpu_waves_per_eu(4,4) -> 128
// VGPR, no spill), weights read directly from global in a packed
// [ic][ky][ocg][20] layout (no LDS weight staging, no transpose barriers),
// hs prefetched through registers (latency hidden by compute).
// ---------------------------------------------------------------------------

// ======================= conv1: [B,1,28,28] -> [B,256,20,20] relu ==========
__global__ __launch_bounds__(256) void k_conv1(const float* __restrict__ x,
                                               const float* __restrict__ w,
                                               const float* __restrict__ bias,
                                               float* __restrict__ h) {
  const int bid = blockIdx.x;
  const int img = bid >> 2, ocq = bid & 3;          // 64 oc per block
  __shared__ float xs[784];
  __shared__ float ws[64 * 81];
  const int t = threadIdx.x;
  const float4* xg = (const float4*)(x + (size_t)img * 784);
  if (t < 196) ((float4*)xs)[t] = xg[t];
  const float4* wg = (const float4*)(w + (size_t)ocq * 64 * 81);
  for (int i = t; i < 1296; i += 256) ((float4*)ws)[i] = wg[i];
  __syncthreads();
  const int ocl = t & 63, rowg = t >> 6;            // wave-uniform row
  const int oc = ocq * 64 + ocl;
  const float bv = bias[oc];
  float* hb = h + ((size_t)img * 256 + oc) * 400;
#pragma unroll 1
  for (int r = rowg; r < 20; r += 4) {
    float acc[20];
#pragma unroll
    for (int p = 0; p < 20; p++) acc[p] = bv;
#pragma unroll
    for (int ky = 0; ky < 9; ky++) {
      float xr[28];
      const float* xrow = &xs[(r + ky) * 28];       // broadcast reads (free)
#pragma unroll
      for (int q = 0; q < 7; q++) ((float4*)xr)[q] = ((const float4*)xrow)[q];
      float wr[9];
#pragma unroll
      for (int i = 0; i < 9; i++) wr[i] = ws[ocl * 81 + ky * 9 + i];
#pragma unroll
      for (int kx = 0; kx < 9; kx++)
#pragma unroll
        for (int p = 0; p < 20; p++)
          acc[p] = fmaf(wr[kx], xr[p + kx], acc[p]);
    }
#pragma unroll
    for (int p = 0; p < 20; p++) acc[p] = fmaxf(acc[p], 0.f);
#pragma unroll
    for (int q = 0; q < 5; q++) ((float4*)(hb + r * 20))[q] = ((float4*)acc)[q];
  }
}

// === weight repack: pw[oc][ic][ky][kx] -> wP[ic][ky][ocg][20] (18+2 pad) ===
// j = kx*2 + c, oc = ocg*2 + c. Gives 5 aligned dwordx4 per (ic,ky,ocg).
__global__ __launch_bounds__(256) void k_repack(const float* __restrict__ pw,
                                                float* __restrict__ wP) {
  const int ic = blockIdx.x >> 1, half = blockIdx.x & 1;  // 128 oc per half
  __shared__ float tile[81 * 129];                  // [k][ocl], pad -> low conflict
  const int t = threadIdx.x;
  for (int i = t; i < 128 * 81; i += 256) {
    const int ocl = i / 81, k = i - ocl * 81;       // coalesced 81-float runs
    tile[k * 129 + ocl] = pw[((size_t)(half * 128 + ocl) * 256 + ic) * 81 + k];
  }
  __syncthreads();
  for (int idx = t; idx < 9 * 64 * 20; idx += 256) {
    const int ky = idx / 1280;
    const int r = idx - ky * 1280;
    const int ocgl = r / 20, j = r - ocgl * 20;
    float v = 0.f;
    if (j < 18) v = tile[(ky * 9 + (j >> 1)) * 129 + (ocgl * 2 + (j & 1))];
    wP[(((size_t)ic * 9 + ky) * 128 + half * 64 + ocgl) * 20 + j] = v;
  }
}

// ============ prim conv: [B,256,20,20] -> partial [B,256,6,6] (K-quarter) ===
// grid: nimg*4 (imgl=bid>>2, kq=bid&3). block 256 = 128 ocg(2 oc) x 2 rowg(3 rows).
// Weights direct-from-global (L1/L2 served), hs register-prefetched.
#define PQ_STRIDE 2359296
__global__ __launch_bounds__(256) __attribute__((amdgpu_waves_per_eu(4, 4)))
void k_conv2(const float* __restrict__ h, const float* __restrict__ wP,
             const float* __restrict__ bias, float* __restrict__ pout, int c0) {
  const int imgl = blockIdx.x >> 2, kq = blockIdx.x & 3;
  __shared__ float hs[400];
  const int t = threadIdx.x;
  const int ocg = t & 127, rowg = t >> 7;           // rows wave-uniform
  const int oc2 = ocg * 2;
  float acc[2][18];
  if (kq == 0) {
    const float2 bv = *(const float2*)&bias[oc2];
#pragma unroll
    for (int p = 0; p < 18; p++) { acc[0][p] = bv.x; acc[1][p] = bv.y; }
  } else {
#pragma unroll
    for (int p = 0; p < 18; p++) { acc[0][p] = 0.f; acc[1][p] = 0.f; }
  }
  const float* hb = h + (size_t)imgl * 102400 + (size_t)(kq * 64) * 400;
  float4 pf;
  if (t < 100) pf = ((const float4*)hb)[t];         // prefetch ic=0
  const float* wbase = wP + (((size_t)(kq * 64) * 9) * 128 + ocg) * 20;
#pragma unroll 1
  for (int ic = 0; ic < 64; ic++) {
    __syncthreads();                                // prev compute done on hs
    if (t < 100) ((float4*)hs)[t] = pf;
    __syncthreads();                                // hs ready
    if (ic < 63 && t < 100)
      pf = ((const float4*)(hb + (size_t)(ic + 1) * 400))[t];  // hidden by FMAs
    const float* wic = wbase + (size_t)ic * 9 * 128 * 20;
#pragma unroll 3
    for (int s = 0; s < 9; s++) {                   // s = ky
      float wv[20];
      const float4* wsrc = (const float4*)(wic + (size_t)s * 2560);
#pragma unroll
      for (int q = 0; q < 5; q++) ((float4*)wv)[q] = wsrc[q];
#pragma unroll
      for (int rr = 0; rr < 3; rr++) {
        const int y = (rowg * 3 + rr) * 2 + s;      // wave-uniform row
        float xr[20];
        const float4* hrow = (const float4*)&hs[y * 20];
#pragma unroll
        for (int q = 0; q < 5; q++) ((float4*)xr)[q] = hrow[q];  // broadcast
#pragma unroll
        for (int kx = 0; kx < 9; kx++) {
#pragma unroll
          for (int px = 0; px < 6; px++) {
            const float xv = xr[2 * px + kx];
            const int ap = rr * 6 + px;
            acc[0][ap] = fmaf(wv[2 * kx], xv, acc[0][ap]);
            acc[1][ap] = fmaf(wv[2 * kx + 1], xv, acc[1][ap]);
          }
        }
      }
    }
  }
  const int img = c0 + imgl;
  float* pq = pout + (size_t)kq * PQ_STRIDE;
#pragma unroll
  for (int c = 0; c < 2; c++) {
    float* pb = pq + ((size_t)img * 256 + (oc2 + c)) * 36 + rowg * 18;
#pragma unroll
    for (int q = 0; q < 9; q++)
      ((float2*)pb)[q] = make_float2(acc[c][2 * q], acc[c][2 * q + 1]);
  }
}

// ===== squash: sum 4 partials, reshape [B,256,36]->[B,1152,8], squash ======
__global__ __launch_bounds__(256) void k_squash(const float* __restrict__ pq,
                                                float* __restrict__ u) {
  const int gid = blockIdx.x * 256 + threadIdx.x;   // b*1152 + i
  const int b = gid / 1152, i = gid - b * 1152;
  const int cp = i / 36, px = i - cp * 36;
  float s[8];
#pragma unroll
  for (int d = 0; d < 8; d++) {
    const size_t idx = ((size_t)b * 256 + (d * 32 + cp)) * 36 + px;
    s[d] = pq[idx] + pq[PQ_STRIDE + idx] + pq[2 * (size_t)PQ_STRIDE + idx] +
           pq[3 * (size_t)PQ_STRIDE + idx];
  }
  float sq = 0.f;
#pragma unroll
  for (int d = 0; d < 8; d++) sq = fmaf(s[d], s[d], sq);
  const float scale = sq / ((1.f + sq) * sqrtf(sq));
  float o[8];
#pragma unroll
  for (int d = 0; d < 8; d++) o[d] = s[d] * scale;
  float* ub = u + (size_t)gid * 8;
  ((float4*)ub)[0] = ((float4*)o)[0];
  ((float4*)ub)[1] = ((float4*)o)[1];
}

// ======================= routing by agreement (per o,b block) ==============
__device__ __forceinline__ float wsum(float v) {
#pragma unroll
  for (int o = 32; o > 0; o >>= 1) v += __shfl_xor(v, o, 64);
  return v;
}
__device__ __forceinline__ float wmaxr(float v) {
#pragma unroll
  for (int o = 32; o > 0; o >>= 1) v = fmaxf(v, __shfl_xor(v, o, 64));
  return v;
}

__global__ __launch_bounds__(256) void k_route(const float* __restrict__ u,
                                               const float* __restrict__ rw,
                                               float* __restrict__ vecs) {
  const int o = blockIdx.x >> 8, b = blockIdx.x & 255;
  __shared__ float us[9216];
  __shared__ float red[4 * 17];
  __shared__ float redm[4];
  const int t = threadIdx.x;
  const int wave = t >> 6, lane = t & 63;
  {
    const float4* ub = (const float4*)(u + (size_t)b * 9216);
    for (int i = t; i < 2304; i += 256) ((float4*)us)[i] = ub[i];
  }
  __syncthreads();
  float pri[5][16];
  const float* rwo = rw + (size_t)o * 147456;
#pragma unroll
  for (int ci = 0; ci < 5; ci++) {
    const bool valid = (ci < 4) || (t < 128);
    const int i = valid ? (t + ci * 256) : 0;
    const float* rwi = rwo + (size_t)i * 128;
    float a[16];
#pragma unroll
    for (int d = 0; d < 16; d++) a[d] = 0.f;
#pragma unroll
    for (int c = 0; c < 8; c++) {
      const float uv = us[i * 8 + c];
      const float4* r4 = (const float4*)(rwi + c * 16);
      const float4 p0 = r4[0], p1 = r4[1], p2 = r4[2], p3 = r4[3];
      a[0] = fmaf(uv, p0.x, a[0]);  a[1] = fmaf(uv, p0.y, a[1]);
      a[2] = fmaf(uv, p0.z, a[2]);  a[3] = fmaf(uv, p0.w, a[3]);
      a[4] = fmaf(uv, p1.x, a[4]);  a[5] = fmaf(uv, p1.y, a[5]);
      a[6] = fmaf(uv, p1.z, a[6]);  a[7] = fmaf(uv, p1.w, a[7]);
      a[8] = fmaf(uv, p2.x, a[8]);  a[9] = fmaf(uv, p2.y, a[9]);
      a[10] = fmaf(uv, p2.z, a[10]); a[11] = fmaf(uv, p2.w, a[11]);
      a[12] = fmaf(uv, p3.x, a[12]); a[13] = fmaf(uv, p3.y, a[13]);
      a[14] = fmaf(uv, p3.z, a[14]); a[15] = fmaf(uv, p3.w, a[15]);
    }
#pragma unroll
    for (int d = 0; d < 16; d++) pri[ci][d] = valid ? a[d] : 0.f;
  }
  float l[5];
#pragma unroll
  for (int ci = 0; ci < 5; ci++)
    l[ci] = ((ci < 4) || (t < 128)) ? 0.f : -1e30f;  // dummy caps -> exp=0
  float v[16];
#pragma unroll 1
  for (int it = 0; it < 3; it++) {
    float m = l[0];
#pragma unroll
    for (int ci = 1; ci < 5; ci++) m = fmaxf(m, l[ci]);
    m = wmaxr(m);
    if (lane == 0) redm[wave] = m;
    __syncthreads();
    m = fmaxf(fmaxf(redm[0], redm[1]), fmaxf(redm[2], redm[3]));
    float Z = 0.f, S[16];
#pragma unroll
    for (int d = 0; d < 16; d++) S[d] = 0.f;
#pragma unroll
    for (int ci = 0; ci < 5; ci++) {
      const float e = expf(l[ci] - m);
      Z += e;
#pragma unroll
      for (int d = 0; d < 16; d++) S[d] = fmaf(e, pri[ci][d], S[d]);
    }
    Z = wsum(Z);
#pragma unroll
    for (int d = 0; d < 16; d++) S[d] = wsum(S[d]);
    __syncthreads();
    if (lane == 0) {
      red[wave * 17] = Z;
#pragma unroll
      for (int d = 0; d < 16; d++) red[wave * 17 + 1 + d] = S[d];
    }
    __syncthreads();
    const float Zt = red[0] + red[17] + red[34] + red[51];
    float sv[16], sq = 0.f;
#pragma unroll
    for (int d = 0; d < 16; d++) {
      const float sd = (red[1 + d] + red[18 + d] + red[35 + d] + red[52 + d]) / Zt;
      sv[d] = sd;
      sq = fmaf(sd, sd, sq);
    }
    const float scale = sq / ((1.f + sq) * sqrtf(sq));
#pragma unroll
    for (int d = 0; d < 16; d++) v[d] = scale * sv[d];
    if (it < 2) {
#pragma unroll
      for (int ci = 0; ci < 5; ci++) {
        float dot = 0.f;
#pragma unroll
        for (int d = 0; d < 16; d++) dot = fmaf(pri[ci][d], v[d], dot);
        l[ci] += dot;
      }
    }
  }
  if (t == 0) {
    float* vb = vecs + ((size_t)b * 10 + o) * 16;
#pragma unroll
    for (int d = 0; d < 16; d++) vb[d] = v[d];
  }
}

// =============== classes softmax + argmax + selected-vector ================
__global__ __launch_bounds__(64) void k_cls(const float* __restrict__ vecs,
                                            float* __restrict__ out,
                                            float* __restrict__ selvec,
                                            int* __restrict__ amv) {
  const int b = blockIdx.x * 64 + threadIdx.x;
  const float* vb = vecs + (size_t)b * 160;
  float n[10];
#pragma unroll
  for (int o = 0; o < 10; o++) {
    float sq = 0.f;
#pragma unroll
    for (int d = 0; d < 16; d++) { const float xv = vb[o * 16 + d]; sq = fmaf(xv, xv, sq); }
    n[o] = sqrtf(sq);
  }
  float m = n[0];
#pragma unroll
  for (int o = 1; o < 10; o++) m = fmaxf(m, n[o]);
  float e[10], Z = 0.f;
#pragma unroll
  for (int o = 0; o < 10; o++) { e[o] = expf(n[o] - m); Z += e[o]; }
  const float inv = 1.f / Z;
  float cls[10];
#pragma unroll
  for (int o = 0; o < 10; o++) {
    cls[o] = e[o] * inv;
    out[(size_t)b * 10 + o] = cls[o];
  }
  int am = 0;
  float best = cls[0];
#pragma unroll
  for (int o = 1; o < 10; o++)
    if (cls[o] > best) { best = cls[o]; am = o; }   // strict > = first-max (jnp.argmax)
  amv[b] = am;
#pragma unroll
  for (int d = 0; d < 16; d++) selvec[(size_t)b * 16 + d] = vb[am * 16 + d];
}

// ============================= decoder =====================================
__global__ __launch_bounds__(512) void k_dec1(const float* __restrict__ selvec,
                                              const int* __restrict__ amv,
                                              const float* __restrict__ w1,
                                              const float* __restrict__ b1,
                                              float* __restrict__ h1) {
  const int b = blockIdx.x, t = threadIdx.x;
  __shared__ float sv[16];
  __shared__ int ams;
  if (t < 16) sv[t] = selvec[(size_t)b * 16 + t];
  if (t == 0) ams = amv[b];
  __syncthreads();
  const float* wrow = w1 + (size_t)ams * 16 * 512;
  float acc = b1[t];
#pragma unroll
  for (int d = 0; d < 16; d++) acc = fmaf(sv[d], wrow[d * 512 + t], acc);
  h1[(size_t)b * 512 + t] = fmaxf(acc, 0.f);
}

__global__ __launch_bounds__(128) void k_dec2(const float* __restrict__ h1,
                                              const float* __restrict__ w2,
                                              const float* __restrict__ b2,
                                              float* __restrict__ h2) {
  const int nc = blockIdx.x >> 5, bg = blockIdx.x & 31;
  const int t = threadIdx.x;
  const int n = nc * 128 + t;
  const int bs = bg * 8;
  __shared__ float h1s[8 * 512];
  {
    const float4* src = (const float4*)(h1 + (size_t)bs * 512);
    for (int i = t; i < 1024; i += 128) ((float4*)h1s)[i] = src[i];
  }
  __syncthreads();
  float acc[8];
  const float bb = b2[n];
#pragma unroll
  for (int j = 0; j < 8; j++) acc[j] = bb;
#pragma unroll 1
  for (int k = 0; k < 512; k += 4) {
    float wq[4];
#pragma unroll
    for (int q = 0; q < 4; q++) wq[q] = w2[(size_t)(k + q) * 1024 + n];
#pragma unroll
    for (int j = 0; j < 8; j++) {
      const float4 hv = *(const float4*)&h1s[j * 512 + k];
      acc[j] = fmaf(hv.x, wq[0], acc[j]);
      acc[j] = fmaf(hv.y, wq[1], acc[j]);
      acc[j] = fmaf(hv.z, wq[2], acc[j]);
      acc[j] = fmaf(hv.w, wq[3], acc[j]);
    }
  }
#pragma unroll
  for (int j = 0; j < 8; j++) h2[(size_t)(bs + j) * 1024 + n] = fmaxf(acc[j], 0.f);
}

__global__ __launch_bounds__(128) void k_dec3(const float* __restrict__ h2,
                                              const float* __restrict__ w3,
                                              const float* __restrict__ b3,
                                              float* __restrict__ out) {
  const int nc = blockIdx.x >> 5, bg = blockIdx.x & 31;   // grid 7*32
  const int t = threadIdx.x;
  const int bs = bg * 8;
  __shared__ float h2s[8 * 1024];
  {
    const float4* src = (const float4*)(h2 + (size_t)bs * 1024);
    for (int i = t; i < 2048; i += 128) ((float4*)h2s)[i] = src[i];
  }
  __syncthreads();
  if (t >= 112) return;                                   // no barriers after
  const int n = nc * 112 + t;
  float acc[8];
  const float bb = b3[n];
#pragma unroll
  for (int j = 0; j < 8; j++) acc[j] = bb;
#pragma unroll 1
  for (int k = 0; k < 1024; k += 4) {
    float wq[4];
#pragma unroll
    for (int q = 0; q < 4; q++) wq[q] = w3[(size_t)(k + q) * 784 + n];
#pragma unroll
    for (int j = 0; j < 8; j++) {
      const float4 hv = *(const float4*)&h2s[j * 1024 + k];
      acc[j] = fmaf(hv.x, wq[0], acc[j]);
      acc[j] = fmaf(hv.y, wq[1], acc[j]);
      acc[j] = fmaf(hv.z, wq[2], acc[j]);
      acc[j] = fmaf(hv.w, wq[3], acc[j]);
    }
  }
#pragma unroll
  for (int j = 0; j < 8; j++)
    out[(size_t)(bs + j) * 784 + n] = 1.f / (1.f + expf(-acc[j]));
}

// ============================= launcher ====================================
extern "C" void kernel_launch(void* const* d_in, const int* in_sizes, int n_in,
                              void* d_out, int out_size, void* d_ws, size_t ws_size,
                              hipStream_t stream) {
  const float* x   = (const float*)d_in[0];
  const float* c1w = (const float*)d_in[1];
  const float* c1b = (const float*)d_in[2];
  const float* pw  = (const float*)d_in[3];
  const float* pb  = (const float*)d_in[4];
  const float* rw  = (const float*)d_in[5];
  const float* w1  = (const float*)d_in[6];
  const float* b1  = (const float*)d_in[7];
  const float* w2  = (const float*)d_in[8];
  const float* b2  = (const float*)d_in[9];
  const float* w3  = (const float*)d_in[10];
  const float* b3  = (const float*)d_in[11];
  float* out = (float*)d_out;
  float* ws = (float*)d_ws;

  const size_t PQ = 2359296;          // 256*256*36
  const size_t WPF = 256 * 9 * 128 * 20;  // packed prim weights: 5.9M floats
  const size_t fixed_f = WPF + 4 * PQ + PQ + 40960 + 4096 + 256 + 131072 + 262144;
  int chunk = 256;                    // images whose conv1 output fits in ws
  while (chunk > 8 && (fixed_f + (size_t)chunk * 102400) * 4 > ws_size) chunk >>= 1;

  float* wPp   = ws;                                // [ic][ky][ocg][20]
  float* h_buf = wPp + WPF;                         // chunk*102400 floats
  float* pq    = h_buf + (size_t)chunk * 102400;    // 4 partial conv2 buffers
  float* u     = pq + 4 * PQ;                       // [B,1152,8]
  float* vecs  = u + PQ;                            // [B,10,16]
  float* sel   = vecs + 40960;                      // [B,16]
  int*   amv   = (int*)(sel + 4096);                // [B]
  float* h1    = sel + 4096 + 256;                  // [B,512]
  float* h2    = h1 + 131072;                       // [B,1024]

  k_repack<<<dim3(512), dim3(256), 0, stream>>>(pw, wPp);
  for (int c0 = 0; c0 < 256; c0 += chunk) {
    k_conv1<<<dim3(chunk * 4), dim3(256), 0, stream>>>(x + (size_t)c0 * 784, c1w, c1b, h_buf);
    k_conv2<<<dim3(chunk * 4), dim3(256), 0, stream>>>(h_buf, wPp, pb, pq, c0);
  }
  k_squash<<<dim3(1152), dim3(256), 0, stream>>>(pq, u);
  k_route<<<dim3(2560), dim3(256), 0, stream>>>(u, rw, vecs);
  k_cls<<<dim3(4), dim3(64), 0, stream>>>(vecs, out, sel, amv);
  k_dec1<<<dim3(256), dim3(512), 0, stream>>>(sel, amv, w1, b1, h1);
  k_dec2<<<dim3(256), dim3(128), 0, stream>>>(h1, w2, b2, h2);
  k_dec3<<<dim3(224), dim3(128), 0, stream>>>(h2, w3, b3, out + 2560);
}

// Round 4
// 3582.684 us; speedup vs baseline: 1.1232x; 1.1232x over previous
//
#include <hip/hip_runtime.h>
#include <math.h>

// ---------------------------------------------------------------------------
// CapsNet forward, fp32 everywhere (no fp32 MFMA on CDNA4 -> vector ALU).
// R4: k_conv2 v4 — designed to FIT the 64-VGPR budget the allocator insists
// on (3 rounds of evidence): 1 oc/thread (acc18+xr20+wv9 ~57 regs), 512-thr
// blocks, weights via R2's proven LDS staging (FETCH stayed 116 MB there),
// input rows read from global at wave-uniform addresses (no hs buffer).
// ---------------------------------------------------------------------------

// ======================= conv1: [B,1,28,28] -> [B,256,20,20] relu ==========
__global__ __launch_bounds__(256) void k_conv1(const float* __restrict__ x,
                                               const float* __restrict__ w,
                                               const float* __restrict__ bias,
                                               float* __restrict__ h) {
  const int bid = blockIdx.x;
  const int img = bid >> 2, ocq = bid & 3;          // 64 oc per block
  __shared__ float xs[784];
  __shared__ float ws[64 * 81];
  const int t = threadIdx.x;
  const float4* xg = (const float4*)(x + (size_t)img * 784);
  if (t < 196) ((float4*)xs)[t] = xg[t];
  const float4* wg = (const float4*)(w + (size_t)ocq * 64 * 81);
  for (int i = t; i < 1296; i += 256) ((float4*)ws)[i] = wg[i];
  __syncthreads();
  const int ocl = t & 63, rowg = t >> 6;            // wave-uniform row
  const int oc = ocq * 64 + ocl;
  const float bv = bias[oc];
  float* hb = h + ((size_t)img * 256 + oc) * 400;
#pragma unroll 1
  for (int r = rowg; r < 20; r += 4) {
    float acc[20];
#pragma unroll
    for (int p = 0; p < 20; p++) acc[p] = bv;
#pragma unroll
    for (int ky = 0; ky < 9; ky++) {
      float xr[28];
      const float* xrow = &xs[(r + ky) * 28];       // broadcast reads (free)
#pragma unroll
      for (int q = 0; q < 7; q++) ((float4*)xr)[q] = ((const float4*)xrow)[q];
      float wr[9];
#pragma unroll
      for (int i = 0; i < 9; i++) wr[i] = ws[ocl * 81 + ky * 9 + i];
#pragma unroll
      for (int kx = 0; kx < 9; kx++)
#pragma unroll
        for (int p = 0; p < 20; p++)
          acc[p] = fmaf(wr[kx], xr[p + kx], acc[p]);
    }
#pragma unroll
    for (int p = 0; p < 20; p++) acc[p] = fmaxf(acc[p], 0.f);
#pragma unroll
    for (int q = 0; q < 5; q++) ((float4*)(hb + r * 20))[q] = ((float4*)acc)[q];
  }
}

// ====== weight repack: pw[oc][ic][81] -> wR[ic][81][oc]  (R2 version) ======
__global__ __launch_bounds__(256) void k_repack(const float* __restrict__ pw,
                                                float* __restrict__ wR) {
  const int ic = blockIdx.x >> 2, ocq = blockIdx.x & 3;
  __shared__ float tile[81 * 65];                   // pad 65: conflict-free
  const int t = threadIdx.x;
  for (int i = t; i < 81 * 64; i += 256) {
    const int ocl = i / 81, k = i - ocl * 81;       // coalesced-ish 81-chunks
    tile[k * 65 + ocl] = pw[((size_t)(ocq * 64 + ocl) * 256 + ic) * 81 + k];
  }
  __syncthreads();
  const int ocl = t & 63, kr = t >> 6;
  for (int k = kr; k < 81; k += 4)                  // 256 B coalesced writes
    wR[((size_t)ic * 81 + k) * 256 + ocq * 64 + ocl] = tile[k * 65 + ocl];
}

// ============ prim conv: [B,256,20,20] -> partial [B,256,6,6] (K-quarter) ===
// grid: nimg*4 (imgl=bid>>2, kq=bid&3). block 512 = 256 oc x 2 rowg(3 rows).
// Fits 64 VGPR: acc[18]+xr[20]+wv[9]. h rows wave-uniform from global.
#define PQ_STRIDE 2359296
__global__ __launch_bounds__(512, 8)
void k_conv2(const float* __restrict__ h, const float* __restrict__ wR,
             const float* __restrict__ bias, float* __restrict__ pout, int c0) {
  const int imgl = blockIdx.x >> 2, kq = blockIdx.x & 3;
  __shared__ float wT[27 * 256];                    // [k within third][oc]
  const int t = threadIdx.x;
  const int oc = t & 255;
  const int rowg = __builtin_amdgcn_readfirstlane(t >> 8);  // wave-uniform
  float acc[18];
  if (kq == 0) {
    const float bv = bias[oc];
#pragma unroll
    for (int p = 0; p < 18; p++) acc[p] = bv;
  } else {
#pragma unroll
    for (int p = 0; p < 18; p++) acc[p] = 0.f;
  }
  const float* hb = h + (size_t)imgl * 102400 + (size_t)(kq * 64) * 400;
  const float* wbase = wR + (size_t)(kq * 64) * 81 * 256;
#pragma unroll 1
  for (int ic = 0; ic < 64; ic++) {
    const float* hic = hb + (size_t)ic * 400;       // wave-uniform base
#pragma unroll 1
    for (int ph = 0; ph < 3; ph++) {                // ky thirds: 27 k each
      __syncthreads();
      const float4* wsrc = (const float4*)(wbase + ((size_t)ic * 81 + ph * 27) * 256);
      for (int i = t; i < 1728; i += 512) ((float4*)wT)[i] = wsrc[i];
      __syncthreads();
#pragma unroll
      for (int kyl = 0; kyl < 3; kyl++) {
        float wv[9];
#pragma unroll
        for (int kx = 0; kx < 9; kx++)
          wv[kx] = wT[(kyl * 9 + kx) * 256 + oc];   // stride-1, conflict-free
#pragma unroll
        for (int rr = 0; rr < 3; rr++) {
          const int y = (rowg * 3 + rr) * 2 + ph * 3 + kyl;  // uniform
          const float4* hrow = (const float4*)(hic + y * 20);
          float xr[20];
#pragma unroll
          for (int q = 0; q < 5; q++) ((float4*)xr)[q] = hrow[q];  // same-addr
#pragma unroll
          for (int kx = 0; kx < 9; kx++) {
#pragma unroll
            for (int px = 0; px < 6; px++)
              acc[rr * 6 + px] = fmaf(wv[kx], xr[2 * px + kx], acc[rr * 6 + px]);
          }
        }
      }
    }
  }
  const int img = c0 + imgl;
  float* pb = pout + (size_t)kq * PQ_STRIDE + ((size_t)img * 256 + oc) * 36 + rowg * 18;
#pragma unroll
  for (int q = 0; q < 9; q++)
    ((float2*)pb)[q] = make_float2(acc[2 * q], acc[2 * q + 1]);
}

// ===== squash: sum 4 partials, reshape [B,256,36]->[B,1152,8], squash ======
__global__ __launch_bounds__(256) void k_squash(const float* __restrict__ pq,
                                                float* __restrict__ u) {
  const int gid = blockIdx.x * 256 + threadIdx.x;   // b*1152 + i
  const int b = gid / 1152, i = gid - b * 1152;
  const int cp = i / 36, px = i - cp * 36;
  float s[8];
#pragma unroll
  for (int d = 0; d < 8; d++) {
    const size_t idx = ((size_t)b * 256 + (d * 32 + cp)) * 36 + px;
    s[d] = pq[idx] + pq[PQ_STRIDE + idx] + pq[2 * (size_t)PQ_STRIDE + idx] +
           pq[3 * (size_t)PQ_STRIDE + idx];
  }
  float sq = 0.f;
#pragma unroll
  for (int d = 0; d < 8; d++) sq = fmaf(s[d], s[d], sq);
  const float scale = sq / ((1.f + sq) * sqrtf(sq));
  float o[8];
#pragma unroll
  for (int d = 0; d < 8; d++) o[d] = s[d] * scale;
  float* ub = u + (size_t)gid * 8;
  ((float4*)ub)[0] = ((float4*)o)[0];
  ((float4*)ub)[1] = ((float4*)o)[1];
}

// ======================= routing by agreement (per o,b block) ==============
__device__ __forceinline__ float wsum(float v) {
#pragma unroll
  for (int o = 32; o > 0; o >>= 1) v += __shfl_xor(v, o, 64);
  return v;
}
__device__ __forceinline__ float wmaxr(float v) {
#pragma unroll
  for (int o = 32; o > 0; o >>= 1) v = fmaxf(v, __shfl_xor(v, o, 64));
  return v;
}

__global__ __launch_bounds__(256) void k_route(const float* __restrict__ u,
                                               const float* __restrict__ rw,
                                               float* __restrict__ vecs) {
  const int o = blockIdx.x >> 8, b = blockIdx.x & 255;
  __shared__ float us[9216];
  __shared__ float red[4 * 17];
  __shared__ float redm[4];
  const int t = threadIdx.x;
  const int wave = t >> 6, lane = t & 63;
  {
    const float4* ub = (const float4*)(u + (size_t)b * 9216);
    for (int i = t; i < 2304; i += 256) ((float4*)us)[i] = ub[i];
  }
  __syncthreads();
  float pri[5][16];
  const float* rwo = rw + (size_t)o * 147456;
#pragma unroll
  for (int ci = 0; ci < 5; ci++) {
    const bool valid = (ci < 4) || (t < 128);
    const int i = valid ? (t + ci * 256) : 0;
    const float* rwi = rwo + (size_t)i * 128;
    float a[16];
#pragma unroll
    for (int d = 0; d < 16; d++) a[d] = 0.f;
#pragma unroll
    for (int c = 0; c < 8; c++) {
      const float uv = us[i * 8 + c];
      const float4* r4 = (const float4*)(rwi + c * 16);
      const float4 p0 = r4[0], p1 = r4[1], p2 = r4[2], p3 = r4[3];
      a[0] = fmaf(uv, p0.x, a[0]);  a[1] = fmaf(uv, p0.y, a[1]);
      a[2] = fmaf(uv, p0.z, a[2]);  a[3] = fmaf(uv, p0.w, a[3]);
      a[4] = fmaf(uv, p1.x, a[4]);  a[5] = fmaf(uv, p1.y, a[5]);
      a[6] = fmaf(uv, p1.z, a[6]);  a[7] = fmaf(uv, p1.w, a[7]);
      a[8] = fmaf(uv, p2.x, a[8]);  a[9] = fmaf(uv, p2.y, a[9]);
      a[10] = fmaf(uv, p2.z, a[10]); a[11] = fmaf(uv, p2.w, a[11]);
      a[12] = fmaf(uv, p3.x, a[12]); a[13] = fmaf(uv, p3.y, a[13]);
      a[14] = fmaf(uv, p3.z, a[14]); a[15] = fmaf(uv, p3.w, a[15]);
    }
#pragma unroll
    for (int d = 0; d < 16; d++) pri[ci][d] = valid ? a[d] : 0.f;
  }
  float l[5];
#pragma unroll
  for (int ci = 0; ci < 5; ci++)
    l[ci] = ((ci < 4) || (t < 128)) ? 0.f : -1e30f;  // dummy caps -> exp=0
  float v[16];
#pragma unroll 1
  for (int it = 0; it < 3; it++) {
    float m = l[0];
#pragma unroll
    for (int ci = 1; ci < 5; ci++) m = fmaxf(m, l[ci]);
    m = wmaxr(m);
    if (lane == 0) redm[wave] = m;
    __syncthreads();
    m = fmaxf(fmaxf(redm[0], redm[1]), fmaxf(redm[2], redm[3]));
    float Z = 0.f, S[16];
#pragma unroll
    for (int d = 0; d < 16; d++) S[d] = 0.f;
#pragma unroll
    for (int ci = 0; ci < 5; ci++) {
      const float e = expf(l[ci] - m);
      Z += e;
#pragma unroll
      for (int d = 0; d < 16; d++) S[d] = fmaf(e, pri[ci][d], S[d]);
    }
    Z = wsum(Z);
#pragma unroll
    for (int d = 0; d < 16; d++) S[d] = wsum(S[d]);
    __syncthreads();
    if (lane == 0) {
      red[wave * 17] = Z;
#pragma unroll
      for (int d = 0; d < 16; d++) red[wave * 17 + 1 + d] = S[d];
    }
    __syncthreads();
    const float Zt = red[0] + red[17] + red[34] + red[51];
    float sv[16], sq = 0.f;
#pragma unroll
    for (int d = 0; d < 16; d++) {
      const float sd = (red[1 + d] + red[18 + d] + red[35 + d] + red[52 + d]) / Zt;
      sv[d] = sd;
      sq = fmaf(sd, sd, sq);
    }
    const float scale = sq / ((1.f + sq) * sqrtf(sq));
#pragma unroll
    for (int d = 0; d < 16; d++) v[d] = scale * sv[d];
    if (it < 2) {
#pragma unroll
      for (int ci = 0; ci < 5; ci++) {
        float dot = 0.f;
#pragma unroll
        for (int d = 0; d < 16; d++) dot = fmaf(pri[ci][d], v[d], dot);
        l[ci] += dot;
      }
    }
  }
  if (t == 0) {
    float* vb = vecs + ((size_t)b * 10 + o) * 16;
#pragma unroll
    for (int d = 0; d < 16; d++) vb[d] = v[d];
  }
}

// =============== classes softmax + argmax + selected-vector ================
__global__ __launch_bounds__(64) void k_cls(const float* __restrict__ vecs,
                                            float* __restrict__ out,
                                            float* __restrict__ selvec,
                                            int* __restrict__ amv) {
  const int b = blockIdx.x * 64 + threadIdx.x;
  const float* vb = vecs + (size_t)b * 160;
  float n[10];
#pragma unroll
  for (int o = 0; o < 10; o++) {
    float sq = 0.f;
#pragma unroll
    for (int d = 0; d < 16; d++) { const float xv = vb[o * 16 + d]; sq = fmaf(xv, xv, sq); }
    n[o] = sqrtf(sq);
  }
  float m = n[0];
#pragma unroll
  for (int o = 1; o < 10; o++) m = fmaxf(m, n[o]);
  float e[10], Z = 0.f;
#pragma unroll
  for (int o = 0; o < 10; o++) { e[o] = expf(n[o] - m); Z += e[o]; }
  const float inv = 1.f / Z;
  float cls[10];
#pragma unroll
  for (int o = 0; o < 10; o++) {
    cls[o] = e[o] * inv;
    out[(size_t)b * 10 + o] = cls[o];
  }
  int am = 0;
  float best = cls[0];
#pragma unroll
  for (int o = 1; o < 10; o++)
    if (cls[o] > best) { best = cls[o]; am = o; }   // strict > = first-max (jnp.argmax)
  amv[b] = am;
#pragma unroll
  for (int d = 0; d < 16; d++) selvec[(size_t)b * 16 + d] = vb[am * 16 + d];
}

// ============================= decoder =====================================
__global__ __launch_bounds__(512) void k_dec1(const float* __restrict__ selvec,
                                              const int* __restrict__ amv,
                                              const float* __restrict__ w1,
                                              const float* __restrict__ b1,
                                              float* __restrict__ h1) {
  const int b = blockIdx.x, t = threadIdx.x;
  __shared__ float sv[16];
  __shared__ int ams;
  if (t < 16) sv[t] = selvec[(size_t)b * 16 + t];
  if (t == 0) ams = amv[b];
  __syncthreads();
  const float* wrow = w1 + (size_t)ams * 16 * 512;
  float acc = b1[t];
#pragma unroll
  for (int d = 0; d < 16; d++) acc = fmaf(sv[d], wrow[d * 512 + t], acc);
  h1[(size_t)b * 512 + t] = fmaxf(acc, 0.f);
}

__global__ __launch_bounds__(128) void k_dec2(const float* __restrict__ h1,
                                              const float* __restrict__ w2,
                                              const float* __restrict__ b2,
                                              float* __restrict__ h2) {
  const int nc = blockIdx.x >> 5, bg = blockIdx.x & 31;
  const int t = threadIdx.x;
  const int n = nc * 128 + t;
  const int bs = bg * 8;
  __shared__ float h1s[8 * 512];
  {
    const float4* src = (const float4*)(h1 + (size_t)bs * 512);
    for (int i = t; i < 1024; i += 128) ((float4*)h1s)[i] = src[i];
  }
  __syncthreads();
  float acc[8];
  const float bb = b2[n];
#pragma unroll
  for (int j = 0; j < 8; j++) acc[j] = bb;
#pragma unroll 1
  for (int k = 0; k < 512; k += 4) {
    float wq[4];
#pragma unroll
    for (int q = 0; q < 4; q++) wq[q] = w2[(size_t)(k + q) * 1024 + n];
#pragma unroll
    for (int j = 0; j < 8; j++) {
      const float4 hv = *(const float4*)&h1s[j * 512 + k];
      acc[j] = fmaf(hv.x, wq[0], acc[j]);
      acc[j] = fmaf(hv.y, wq[1], acc[j]);
      acc[j] = fmaf(hv.z, wq[2], acc[j]);
      acc[j] = fmaf(hv.w, wq[3], acc[j]);
    }
  }
#pragma unroll
  for (int j = 0; j < 8; j++) h2[(size_t)(bs + j) * 1024 + n] = fmaxf(acc[j], 0.f);
}

__global__ __launch_bounds__(128) void k_dec3(const float* __restrict__ h2,
                                              const float* __restrict__ w3,
                                              const float* __restrict__ b3,
                                              float* __restrict__ out) {
  const int nc = blockIdx.x >> 5, bg = blockIdx.x & 31;   // grid 7*32
  const int t = threadIdx.x;
  const int bs = bg * 8;
  __shared__ float h2s[8 * 1024];
  {
    const float4* src = (const float4*)(h2 + (size_t)bs * 1024);
    for (int i = t; i < 2048; i += 128) ((float4*)h2s)[i] = src[i];
  }
  __syncthreads();
  if (t >= 112) return;                                   // no barriers after
  const int n = nc * 112 + t;
  float acc[8];
  const float bb = b3[n];
#pragma unroll
  for (int j = 0; j < 8; j++) acc[j] = bb;
#pragma unroll 1
  for (int k = 0; k < 1024; k += 4) {
    float wq[4];
#pragma unroll
    for (int q = 0; q < 4; q++) wq[q] = w3[(size_t)(k + q) * 784 + n];
#pragma unroll
    for (int j = 0; j < 8; j++) {
      const float4 hv = *(const float4*)&h2s[j * 1024 + k];
      acc[j] = fmaf(hv.x, wq[0], acc[j]);
      acc[j] = fmaf(hv.y, wq[1], acc[j]);
      acc[j] = fmaf(hv.z, wq[2], acc[j]);
      acc[j] = fmaf(hv.w, wq[3], acc[j]);
    }
  }
#pragma unroll
  for (int j = 0; j < 8; j++)
    out[(size_t)(bs + j) * 784 + n] = 1.f / (1.f + expf(-acc[j]));
}

// ============================= launcher ====================================
extern "C" void kernel_launch(void* const* d_in, const int* in_sizes, int n_in,
                              void* d_out, int out_size, void* d_ws, size_t ws_size,
                              hipStream_t stream) {
  const float* x   = (const float*)d_in[0];
  const float* c1w = (const float*)d_in[1];
  const float* c1b = (const float*)d_in[2];
  const float* pw  = (const float*)d_in[3];
  const float* pb  = (const float*)d_in[4];
  const float* rw  = (const float*)d_in[5];
  const float* w1  = (const float*)d_in[6];
  const float* b1  = (const float*)d_in[7];
  const float* w2  = (const float*)d_in[8];
  const float* b2  = (const float*)d_in[9];
  const float* w3  = (const float*)d_in[10];
  const float* b3  = (const float*)d_in[11];
  float* out = (float*)d_out;
  float* ws = (float*)d_ws;

  const size_t PQ = 2359296;          // 256*256*36
  const size_t WRF = 256 * 81 * 256;  // repacked prim weights: 5.3M floats
  const size_t fixed_f = WRF + 4 * PQ + PQ + 40960 + 4096 + 256 + 131072 + 262144;
  int chunk = 256;                    // images whose conv1 output fits in ws
  while (chunk > 8 && (fixed_f + (size_t)chunk * 102400) * 4 > ws_size) chunk >>= 1;

  float* wRp   = ws;                                // [ic][81][oc]
  float* h_buf = wRp + WRF;                         // chunk*102400 floats
  float* pq    = h_buf + (size_t)chunk * 102400;    // 4 partial conv2 buffers
  float* u     = pq + 4 * PQ;                       // [B,1152,8]
  float* vecs  = u + PQ;                            // [B,10,16]
  float* sel   = vecs + 40960;                      // [B,16]
  int*   amv   = (int*)(sel + 4096);                // [B]
  float* h1    = sel + 4096 + 256;                  // [B,512]
  float* h2    = h1 + 131072;                       // [B,1024]

  k_repack<<<dim3(1024), dim3(256), 0, stream>>>(pw, wRp);
  for (int c0 = 0; c0 < 256; c0 += chunk) {
    k_conv1<<<dim3(chunk * 4), dim3(256), 0, stream>>>(x + (size_t)c0 * 784, c1w, c1b, h_buf);
    k_conv2<<<dim3(chunk * 4), dim3(512), 0, stream>>>(h_buf, wRp, pb, pq, c0);
  }
  k_squash<<<dim3(1152), dim3(256), 0, stream>>>(pq, u);
  k_route<<<dim3(2560), dim3(256), 0, stream>>>(u, rw, vecs);
  k_cls<<<dim3(4), dim3(64), 0, stream>>>(vecs, out, sel, amv);
  k_dec1<<<dim3(256), dim3(512), 0, stream>>>(sel, amv, w1, b1, h1);
  k_dec2<<<dim3(256), dim3(128), 0, stream>>>(h1, w2, b2, h2);
  k_dec3<<<dim3(224), dim3(128), 0, stream>>>(h2, w3, b3, out + 2560);
}

// Round 5
// 1126.243 us; speedup vs baseline: 3.5730x; 3.1811x over previous
//
#include <hip/hip_runtime.h>
#include <hip/hip_bf16.h>
#include <math.h>

// ---------------------------------------------------------------------------
// CapsNet forward. R5: prim-capsule conv rewritten as split-bf16 (hi+lo,
// 3-pass) MFMA GEMM: C[144px, 64oc] per block, K = 84taps x 256ic.
// conv1 emits transposed bf16 hi/lo activations; weights pre-repacked into
// the padded LDS image and streamed via global_load_lds(16B), double-buffered.
// Rationale: 4 rounds of counters show the fp32 path is allocator-capped
// (VGPR halving + scratch spill); MFMA puts accumulators in AGPRs where the
// 50/50 split works FOR us, at 10x the FLOP rate.
// ---------------------------------------------------------------------------

typedef __attribute__((ext_vector_type(8))) short bf16x8;
typedef __attribute__((ext_vector_type(4))) float f32x4;

__device__ __forceinline__ void gl16(const void* g, void* l) {
  __builtin_amdgcn_global_load_lds((const __attribute__((address_space(1))) void*)g,
                                   (__attribute__((address_space(3))) void*)l,
                                   16, 0, 0);
}

// ======== conv1: [B,1,28,28] -> hTgc[img][ch32][yx400][8hi|8lo] bf16 =======
__global__ __launch_bounds__(256) void k_conv1(const float* __restrict__ x,
                                               const float* __restrict__ w,
                                               const float* __restrict__ bias,
                                               __hip_bfloat16* __restrict__ hT) {
  const int bid = blockIdx.x;
  const int img = bid >> 2, ocq = bid & 3;          // 64 oc per block
  __shared__ float xs[784];
  __shared__ float ws[64 * 81];
  const int t = threadIdx.x;
  const float4* xg = (const float4*)(x + (size_t)img * 784);
  if (t < 196) ((float4*)xs)[t] = xg[t];
  const float4* wg = (const float4*)(w + (size_t)ocq * 64 * 81);
  for (int i = t; i < 1296; i += 256) ((float4*)ws)[i] = wg[i];
  __syncthreads();
  const int ocl = t & 63, rowg = t >> 6;            // wave-uniform row
  const int oc = ocq * 64 + ocl;
  const int ch = oc >> 3, icl = oc & 7;
  const float bv = bias[oc];
  __hip_bfloat16* hb = hT + ((size_t)img * 32 + ch) * 400 * 16 + icl;
#pragma unroll 1
  for (int r = rowg; r < 20; r += 4) {
    float acc[20];
#pragma unroll
    for (int p = 0; p < 20; p++) acc[p] = bv;
#pragma unroll
    for (int ky = 0; ky < 9; ky++) {
      float xr[28];
      const float* xrow = &xs[(r + ky) * 28];       // broadcast reads
#pragma unroll
      for (int q = 0; q < 7; q++) ((float4*)xr)[q] = ((const float4*)xrow)[q];
      float wr[9];
#pragma unroll
      for (int i = 0; i < 9; i++) wr[i] = ws[ocl * 81 + ky * 9 + i];
#pragma unroll
      for (int kx = 0; kx < 9; kx++)
#pragma unroll
        for (int p = 0; p < 20; p++)
          acc[p] = fmaf(wr[kx], xr[p + kx], acc[p]);
    }
#pragma unroll
    for (int p = 0; p < 20; p++) {
      const float v = fmaxf(acc[p], 0.f);
      const __hip_bfloat16 hi = __float2bfloat16(v);
      const __hip_bfloat16 lo = __float2bfloat16(v - __bfloat162float(hi));
      __hip_bfloat16* dst = hb + (size_t)(r * 20 + p) * 16;
      dst[0] = hi;
      dst[8] = lo;
    }
  }
}

// ==== weight repack: pw[oc][ic][81] -> wGp[step672][ocq4][oc64][32hi|32lo|8z]
__global__ __launch_bounds__(256) void k_wrep(const float* __restrict__ pw,
                                              __hip_bfloat16* __restrict__ wGp) {
  const int s = blockIdx.x >> 2, ocq = blockIdx.x & 3;   // s in [0,672)
  const int ch = s / 21, tq = s - ch * 21;
  __hip_bfloat16* outp = wGp + ((size_t)s * 4 + ocq) * 4608;
  const int t = threadIdx.x;
  for (int e = t; e < 2048; e += 256) {
    const int ocl = e >> 5, k = e & 31;
    const int tapl = k >> 3, icl = k & 7;
    const int tap = tq * 4 + tapl, ic = ch * 8 + icl;
    const int oc = ocq * 64 + ocl;
    const float v = (tap < 81) ? pw[((size_t)oc * 256 + ic) * 81 + tap] : 0.f;
    const __hip_bfloat16 hi = __float2bfloat16(v);
    const __hip_bfloat16 lo = __float2bfloat16(v - __bfloat162float(hi));
    outp[ocl * 72 + k] = hi;
    outp[ocl * 72 + 32 + k] = lo;
  }
  for (int e = t; e < 512; e += 256) {                   // zero the row pads
    const int ocl = e >> 3, j = e & 7;
    outp[ocl * 72 + 64 + j] = __float2bfloat16(0.f);
  }
}

// ============ conv2 MFMA: p[img][px36][oc256] = conv(hT, w) + bias ==========
// block 512 thr = 8 waves: wave = (mhalf, oc16). 4 img (M=144 = 9 tiles).
// K-step 32 = 4 taps x 8 ic; 672 steps. acc += Ahi*Bhi + Ahi*Blo + Alo*Bhi.
#define HT_BYTES 51200          // 1600 rows x 32B (8 hi + 8 lo bf16)
#define WS_BYTES 9216           // 64 oc x 144B (32hi|32lo|8pad bf16)
__global__ __launch_bounds__(512) void k_conv2(
    const __hip_bfloat16* __restrict__ hTgc,   // [chunk img][32ch][400][16]
    const __hip_bfloat16* __restrict__ wGp,    // [672][4ocq][4608]
    const float* __restrict__ pb,
    float* __restrict__ p, int c0) {
  __shared__ char smem[HT_BYTES + 2 * WS_BYTES];
  char* hT = smem;
  char* wS = smem + HT_BYTES;
  const int t = threadIdx.x;
  const int ig = blockIdx.x >> 2, ocq = blockIdx.x & 3;
  const int w = t >> 6, lane = t & 63;
  const int lquad = lane >> 4, lrow = lane & 15;
  const int mhalf = w >> 2;
  const int nt = mhalf ? 4 : 5;                 // tiles 0..4 / 5..8
  const int mtb = mhalf ? 5 : 0;
  const int ocg = ocq * 64 + (w & 3) * 16 + lrow;
  int abase[5];
#pragma unroll
  for (int i = 0; i < 5; i++) {
    int m = (mtb + i) * 16 + lrow;
    if (i >= nt) m = 0;
    const int img = m / 36, px = m - img * 36;
    const int oy = px / 6, ox = px - oy * 6;
    abase[i] = (img * 400 + oy * 40 + ox * 2) * 32;   // bytes
  }
  f32x4 acc[5];
#pragma unroll
  for (int i = 0; i < 5; i++) acc[i] = (f32x4){0.f, 0.f, 0.f, 0.f};

  const __hip_bfloat16* hbase = hTgc + (size_t)(ig * 4) * (32 * 400 * 16);
  // pre-stage W step 0 into buf 0
  {
    const char* g = (const char*)wGp + (size_t)ocq * 9216;
    gl16(g + t * 16, wS + w * 1024);
    if (t < 64) gl16(g + 8192 + lane * 16, wS + 8192);
  }
  int step = 0;
#pragma unroll 1
  for (int ch = 0; ch < 32; ch++) {
    // stage hT(ch): 3200 x 16B units, lds[idx*16] <- hTgc row halves
#pragma unroll
    for (int rr = 0; rr < 6; rr++) {
      const int idx = t + rr * 512;
      const int row = idx >> 1, half = idx & 1;
      const int img = row / 400, yx = row - img * 400;
      const char* g = (const char*)(hbase + ((size_t)(img * 32 + ch) * 400 + yx) * 16) + half * 16;
      gl16(g, hT + rr * 8192 + w * 1024);
    }
    if (t < 128) {
      const int idx = t + 3072;
      const int row = idx >> 1, half = idx & 1;
      const int img = row / 400, yx = row - img * 400;
      const char* g = (const char*)(hbase + ((size_t)(img * 32 + ch) * 400 + yx) * 16) + half * 16;
      gl16(g, hT + 6 * 8192 + w * 1024);
    }
    __syncthreads();
#pragma unroll 1
    for (int tq = 0; tq < 21; tq++) {
      const int buf = step & 1;
      if (step + 1 < 672) {                      // prefetch next W slice
        const char* g = (const char*)wGp + (size_t)(step + 1) * 36864 + ocq * 9216;
        gl16(g + t * 16, wS + (buf ^ 1) * WS_BYTES + w * 1024);
        if (t < 64) gl16(g + 8192 + lane * 16, wS + (buf ^ 1) * WS_BYTES + 8192);
      }
      const char* wrow = wS + buf * WS_BYTES + ((w & 3) * 16 + lrow) * 144 + lquad * 16;
      const bf16x8 bh = *(const bf16x8*)(wrow);
      const bf16x8 bl = *(const bf16x8*)(wrow + 64);
      const int tt = tq * 4 + lquad;             // this quad's tap
      const int ky = tt / 9, kx = tt - ky * 9;
      const int toff = (ky * 20 + kx) * 32;
      bf16x8 ah[5], al[5];
#pragma unroll
      for (int i = 0; i < 5; i++) {
        const char* a = hT + abase[i] + toff;
        ah[i] = *(const bf16x8*)(a);
        al[i] = *(const bf16x8*)(a + 16);
      }
#pragma unroll
      for (int i = 0; i < 5; i++)
        if (i < nt) acc[i] = __builtin_amdgcn_mfma_f32_16x16x32_bf16(ah[i], bh, acc[i], 0, 0, 0);
#pragma unroll
      for (int i = 0; i < 5; i++)
        if (i < nt) acc[i] = __builtin_amdgcn_mfma_f32_16x16x32_bf16(ah[i], bl, acc[i], 0, 0, 0);
#pragma unroll
      for (int i = 0; i < 5; i++)
        if (i < nt) acc[i] = __builtin_amdgcn_mfma_f32_16x16x32_bf16(al[i], bh, acc[i], 0, 0, 0);
      step++;
      __syncthreads();
    }
  }
  const float bias = pb[ocg];
  float* pblk = p + (size_t)(c0 + ig * 4) * 36 * 256 + ocg;
#pragma unroll
  for (int i = 0; i < 5; i++) {
    if (i < nt) {
#pragma unroll
      for (int r = 0; r < 4; r++) {
        const int m = (mtb + i) * 16 + lquad * 4 + r;   // D row = quad*4+reg
        const int img = m / 36, px = m - img * 36;
        pblk[((size_t)img * 36 + px) * 256] = acc[i][r] + bias;
      }
    }
  }
}

// ===== squash: p[b][px][oc] -> u[b][i=cp*36+px][d], squash over d ==========
__global__ __launch_bounds__(256) void k_squash(const float* __restrict__ p,
                                                float* __restrict__ u) {
  const int gid = blockIdx.x * 256 + threadIdx.x;   // b*1152 + i
  const int b = gid / 1152, i = gid - b * 1152;
  const int cp = i / 36, px = i - cp * 36;
  const float* pb = p + ((size_t)b * 36 + px) * 256 + cp;
  float s[8];
#pragma unroll
  for (int d = 0; d < 8; d++) s[d] = pb[d * 32];
  float sq = 0.f;
#pragma unroll
  for (int d = 0; d < 8; d++) sq = fmaf(s[d], s[d], sq);
  const float scale = sq / ((1.f + sq) * sqrtf(sq));
  float o[8];
#pragma unroll
  for (int d = 0; d < 8; d++) o[d] = s[d] * scale;
  float* ub = u + (size_t)gid * 8;
  ((float4*)ub)[0] = ((float4*)o)[0];
  ((float4*)ub)[1] = ((float4*)o)[1];
}

// ======================= routing by agreement (per o,b block) ==============
__device__ __forceinline__ float wsum(float v) {
#pragma unroll
  for (int o = 32; o > 0; o >>= 1) v += __shfl_xor(v, o, 64);
  return v;
}
__device__ __forceinline__ float wmaxr(float v) {
#pragma unroll
  for (int o = 32; o > 0; o >>= 1) v = fmaxf(v, __shfl_xor(v, o, 64));
  return v;
}

__global__ __launch_bounds__(256) void k_route(const float* __restrict__ u,
                                               const float* __restrict__ rw,
                                               float* __restrict__ vecs) {
  const int o = blockIdx.x >> 8, b = blockIdx.x & 255;
  __shared__ float us[9216];
  __shared__ float red[4 * 17];
  __shared__ float redm[4];
  const int t = threadIdx.x;
  const int wave = t >> 6, lane = t & 63;
  {
    const float4* ub = (const float4*)(u + (size_t)b * 9216);
    for (int i = t; i < 2304; i += 256) ((float4*)us)[i] = ub[i];
  }
  __syncthreads();
  float pri[5][16];
  const float* rwo = rw + (size_t)o * 147456;
#pragma unroll
  for (int ci = 0; ci < 5; ci++) {
    const bool valid = (ci < 4) || (t < 128);
    const int i = valid ? (t + ci * 256) : 0;
    const float* rwi = rwo + (size_t)i * 128;
    float a[16];
#pragma unroll
    for (int d = 0; d < 16; d++) a[d] = 0.f;
#pragma unroll
    for (int c = 0; c < 8; c++) {
      const float uv = us[i * 8 + c];
      const float4* r4 = (const float4*)(rwi + c * 16);
      const float4 p0 = r4[0], p1 = r4[1], p2 = r4[2], p3 = r4[3];
      a[0] = fmaf(uv, p0.x, a[0]);  a[1] = fmaf(uv, p0.y, a[1]);
      a[2] = fmaf(uv, p0.z, a[2]);  a[3] = fmaf(uv, p0.w, a[3]);
      a[4] = fmaf(uv, p1.x, a[4]);  a[5] = fmaf(uv, p1.y, a[5]);
      a[6] = fmaf(uv, p1.z, a[6]);  a[7] = fmaf(uv, p1.w, a[7]);
      a[8] = fmaf(uv, p2.x, a[8]);  a[9] = fmaf(uv, p2.y, a[9]);
      a[10] = fmaf(uv, p2.z, a[10]); a[11] = fmaf(uv, p2.w, a[11]);
      a[12] = fmaf(uv, p3.x, a[12]); a[13] = fmaf(uv, p3.y, a[13]);
      a[14] = fmaf(uv, p3.z, a[14]); a[15] = fmaf(uv, p3.w, a[15]);
    }
#pragma unroll
    for (int d = 0; d < 16; d++) pri[ci][d] = valid ? a[d] : 0.f;
  }
  float l[5];
#pragma unroll
  for (int ci = 0; ci < 5; ci++)
    l[ci] = ((ci < 4) || (t < 128)) ? 0.f : -1e30f;
  float v[16];
#pragma unroll 1
  for (int it = 0; it < 3; it++) {
    float m = l[0];
#pragma unroll
    for (int ci = 1; ci < 5; ci++) m = fmaxf(m, l[ci]);
    m = wmaxr(m);
    if (lane == 0) redm[wave] = m;
    __syncthreads();
    m = fmaxf(fmaxf(redm[0], redm[1]), fmaxf(redm[2], redm[3]));
    float Z = 0.f, S[16];
#pragma unroll
    for (int d = 0; d < 16; d++) S[d] = 0.f;
#pragma unroll
    for (int ci = 0; ci < 5; ci++) {
      const float e = expf(l[ci] - m);
      Z += e;
#pragma unroll
      for (int d = 0; d < 16; d++) S[d] = fmaf(e, pri[ci][d], S[d]);
    }
    Z = wsum(Z);
#pragma unroll
    for (int d = 0; d < 16; d++) S[d] = wsum(S[d]);
    __syncthreads();
    if (lane == 0) {
      red[wave * 17] = Z;
#pragma unroll
      for (int d = 0; d < 16; d++) red[wave * 17 + 1 + d] = S[d];
    }
    __syncthreads();
    const float Zt = red[0] + red[17] + red[34] + red[51];
    float sv[16], sq = 0.f;
#pragma unroll
    for (int d = 0; d < 16; d++) {
      const float sd = (red[1 + d] + red[18 + d] + red[35 + d] + red[52 + d]) / Zt;
      sv[d] = sd;
      sq = fmaf(sd, sd, sq);
    }
    const float scale = sq / ((1.f + sq) * sqrtf(sq));
#pragma unroll
    for (int d = 0; d < 16; d++) v[d] = scale * sv[d];
    if (it < 2) {
#pragma unroll
      for (int ci = 0; ci < 5; ci++) {
        float dot = 0.f;
#pragma unroll
        for (int d = 0; d < 16; d++) dot = fmaf(pri[ci][d], v[d], dot);
        l[ci] += dot;
      }
    }
  }
  if (t == 0) {
    float* vb = vecs + ((size_t)b * 10 + o) * 16;
#pragma unroll
    for (int d = 0; d < 16; d++) vb[d] = v[d];
  }
}

// =============== classes softmax + argmax + selected-vector ================
__global__ __launch_bounds__(64) void k_cls(const float* __restrict__ vecs,
                                            float* __restrict__ out,
                                            float* __restrict__ selvec,
                                            int* __restrict__ amv) {
  const int b = blockIdx.x * 64 + threadIdx.x;
  const float* vb = vecs + (size_t)b * 160;
  float n[10];
#pragma unroll
  for (int o = 0; o < 10; o++) {
    float sq = 0.f;
#pragma unroll
    for (int d = 0; d < 16; d++) { const float xv = vb[o * 16 + d]; sq = fmaf(xv, xv, sq); }
    n[o] = sqrtf(sq);
  }
  float m = n[0];
#pragma unroll
  for (int o = 1; o < 10; o++) m = fmaxf(m, n[o]);
  float e[10], Z = 0.f;
#pragma unroll
  for (int o = 0; o < 10; o++) { e[o] = expf(n[o] - m); Z += e[o]; }
  const float inv = 1.f / Z;
  float cls[10];
#pragma unroll
  for (int o = 0; o < 10; o++) {
    cls[o] = e[o] * inv;
    out[(size_t)b * 10 + o] = cls[o];
  }
  int am = 0;
  float best = cls[0];
#pragma unroll
  for (int o = 1; o < 10; o++)
    if (cls[o] > best) { best = cls[o]; am = o; }
  amv[b] = am;
#pragma unroll
  for (int d = 0; d < 16; d++) selvec[(size_t)b * 16 + d] = vb[am * 16 + d];
}

// ============================= decoder =====================================
__global__ __launch_bounds__(512) void k_dec1(const float* __restrict__ selvec,
                                              const int* __restrict__ amv,
                                              const float* __restrict__ w1,
                                              const float* __restrict__ b1,
                                              float* __restrict__ h1) {
  const int b = blockIdx.x, t = threadIdx.x;
  __shared__ float sv[16];
  __shared__ int ams;
  if (t < 16) sv[t] = selvec[(size_t)b * 16 + t];
  if (t == 0) ams = amv[b];
  __syncthreads();
  const float* wrow = w1 + (size_t)ams * 16 * 512;
  float acc = b1[t];
#pragma unroll
  for (int d = 0; d < 16; d++) acc = fmaf(sv[d], wrow[d * 512 + t], acc);
  h1[(size_t)b * 512 + t] = fmaxf(acc, 0.f);
}

__global__ __launch_bounds__(128) void k_dec2(const float* __restrict__ h1,
                                              const float* __restrict__ w2,
                                              const float* __restrict__ b2,
                                              float* __restrict__ h2) {
  const int nc = blockIdx.x >> 5, bg = blockIdx.x & 31;
  const int t = threadIdx.x;
  const int n = nc * 128 + t;
  const int bs = bg * 8;
  __shared__ float h1s[8 * 512];
  {
    const float4* src = (const float4*)(h1 + (size_t)bs * 512);
    for (int i = t; i < 1024; i += 128) ((float4*)h1s)[i] = src[i];
  }
  __syncthreads();
  float acc[8];
  const float bb = b2[n];
#pragma unroll
  for (int j = 0; j < 8; j++) acc[j] = bb;
#pragma unroll 1
  for (int k = 0; k < 512; k += 4) {
    float wq[4];
#pragma unroll
    for (int q = 0; q < 4; q++) wq[q] = w2[(size_t)(k + q) * 1024 + n];
#pragma unroll
    for (int j = 0; j < 8; j++) {
      const float4 hv = *(const float4*)&h1s[j * 512 + k];
      acc[j] = fmaf(hv.x, wq[0], acc[j]);
      acc[j] = fmaf(hv.y, wq[1], acc[j]);
      acc[j] = fmaf(hv.z, wq[2], acc[j]);
      acc[j] = fmaf(hv.w, wq[3], acc[j]);
    }
  }
#pragma unroll
  for (int j = 0; j < 8; j++) h2[(size_t)(bs + j) * 1024 + n] = fmaxf(acc[j], 0.f);
}

__global__ __launch_bounds__(128) void k_dec3(const float* __restrict__ h2,
                                              const float* __restrict__ w3,
                                              const float* __restrict__ b3,
                                              float* __restrict__ out) {
  const int nc = blockIdx.x >> 5, bg = blockIdx.x & 31;   // grid 7*32
  const int t = threadIdx.x;
  const int bs = bg * 8;
  __shared__ float h2s[8 * 1024];
  {
    const float4* src = (const float4*)(h2 + (size_t)bs * 1024);
    for (int i = t; i < 2048; i += 128) ((float4*)h2s)[i] = src[i];
  }
  __syncthreads();
  if (t >= 112) return;
  const int n = nc * 112 + t;
  float acc[8];
  const float bb = b3[n];
#pragma unroll
  for (int j = 0; j < 8; j++) acc[j] = bb;
#pragma unroll 1
  for (int k = 0; k < 1024; k += 4) {
    float wq[4];
#pragma unroll
    for (int q = 0; q < 4; q++) wq[q] = w3[(size_t)(k + q) * 784 + n];
#pragma unroll
    for (int j = 0; j < 8; j++) {
      const float4 hv = *(const float4*)&h2s[j * 1024 + k];
      acc[j] = fmaf(hv.x, wq[0], acc[j]);
      acc[j] = fmaf(hv.y, wq[1], acc[j]);
      acc[j] = fmaf(hv.z, wq[2], acc[j]);
      acc[j] = fmaf(hv.w, wq[3], acc[j]);
    }
  }
#pragma unroll
  for (int j = 0; j < 8; j++)
    out[(size_t)(bs + j) * 784 + n] = 1.f / (1.f + expf(-acc[j]));
}

// ============================= launcher ====================================
extern "C" void kernel_launch(void* const* d_in, const int* in_sizes, int n_in,
                              void* d_out, int out_size, void* d_ws, size_t ws_size,
                              hipStream_t stream) {
  const float* x   = (const float*)d_in[0];
  const float* c1w = (const float*)d_in[1];
  const float* c1b = (const float*)d_in[2];
  const float* pw  = (const float*)d_in[3];
  const float* pb  = (const float*)d_in[4];
  const float* rw  = (const float*)d_in[5];
  const float* w1  = (const float*)d_in[6];
  const float* b1  = (const float*)d_in[7];
  const float* w2  = (const float*)d_in[8];
  const float* b2  = (const float*)d_in[9];
  const float* w3  = (const float*)d_in[10];
  const float* b3  = (const float*)d_in[11];
  float* out = (float*)d_out;
  float* ws = (float*)d_ws;

  const size_t WGP_F = (size_t)672 * 4 * 4608 / 2;     // bf16 pairs as floats
  const size_t P_F = 2359296, U_F = 2359296;
  const size_t SMALL_F = 40960 + 4096 + 256 + 131072 + 262144;
  const size_t fixed_f = WGP_F + P_F + U_F + SMALL_F;
  int chunk = 256;                                     // imgs per pipeline iter
  while (chunk > 4 && (fixed_f + (size_t)chunk * 102400) * 4 > ws_size) chunk >>= 1;

  __hip_bfloat16* wGp  = (__hip_bfloat16*)ws;           // [672][4][4608]
  __hip_bfloat16* hTgc = (__hip_bfloat16*)(ws + WGP_F); // [chunk][32][400][16]
  float* p    = ws + WGP_F + (size_t)chunk * 102400;
  float* u    = p + P_F;
  float* vecs = u + U_F;
  float* sel  = vecs + 40960;
  int*   amv  = (int*)(sel + 4096);
  float* h1   = sel + 4096 + 256;
  float* h2   = h1 + 131072;

  k_wrep<<<dim3(2688), dim3(256), 0, stream>>>(pw, wGp);
  for (int c0 = 0; c0 < 256; c0 += chunk) {
    k_conv1<<<dim3(chunk * 4), dim3(256), 0, stream>>>(x + (size_t)c0 * 784, c1w, c1b, hTgc);
    k_conv2<<<dim3(chunk), dim3(512), 0, stream>>>(hTgc, wGp, pb, p, c0);
  }
  k_squash<<<dim3(1152), dim3(256), 0, stream>>>(p, u);
  k_route<<<dim3(2560), dim3(256), 0, stream>>>(u, rw, vecs);
  k_cls<<<dim3(4), dim3(64), 0, stream>>>(vecs, out, sel, amv);
  k_dec1<<<dim3(256), dim3(512), 0, stream>>>(sel, amv, w1, b1, h1);
  k_dec2<<<dim3(256), dim3(128), 0, stream>>>(h1, w2, b2, h2);
  k_dec3<<<dim3(224), dim3(128), 0, stream>>>(h2, w3, b3, out + 2560);
}

// Round 6
// 892.206 us; speedup vs baseline: 4.5102x; 1.2623x over previous
//
#include <hip/hip_runtime.h>
#include <hip/hip_bf16.h>
#include <math.h>

// ---------------------------------------------------------------------------
// CapsNet forward. R6: conv2 MFMA v2.
//  - hT layout x-major, 41-chunk x-stride: chunk=(img*20+x)*41+y*2+half.
//    A-read lane banks = (2ox+4oy)%8 -> even 4-way spread (R5 layout had 2
//    positions -> 8-way conflict, 1.38e8 conflict cycles = ~40% of dur).
//  - K-split x2 (kq over 16 ch) -> grid 512 -> 2 blocks/CU (barrier overlap);
//    partials summed (+bias) in k_squash. XCD swizzle: 4 ocq sharers of an
//    image-group keep bid%8 constant for hT L2 reuse.
// ---------------------------------------------------------------------------

typedef __attribute__((ext_vector_type(8))) short bf16x8;
typedef __attribute__((ext_vector_type(4))) float f32x4;

__device__ __forceinline__ void gl16(const void* g, void* l) {
  __builtin_amdgcn_global_load_lds((const __attribute__((address_space(1))) void*)g,
                                   (__attribute__((address_space(3))) void*)l,
                                   16, 0, 0);
}

// ==== conv1: [B,1,28,28] -> hTg[img][ch][(x*41+y*2+half) chunk][8 bf16] ====
__global__ __launch_bounds__(256) void k_conv1(const float* __restrict__ x,
                                               const float* __restrict__ w,
                                               const float* __restrict__ bias,
                                               __hip_bfloat16* __restrict__ hT) {
  const int bid = blockIdx.x;
  const int img = bid >> 2, ocq = bid & 3;          // 64 oc per block
  __shared__ float xs[784];
  __shared__ float ws[64 * 81];
  const int t = threadIdx.x;
  const float4* xg = (const float4*)(x + (size_t)img * 784);
  if (t < 196) ((float4*)xs)[t] = xg[t];
  const float4* wg = (const float4*)(w + (size_t)ocq * 64 * 81);
  for (int i = t; i < 1296; i += 256) ((float4*)ws)[i] = wg[i];
  __syncthreads();
  const int ocl = t & 63, rowg = t >> 6;            // wave-uniform row
  const int oc = ocq * 64 + ocl;
  const int ch = oc >> 3, icl = oc & 7;
  const float bv = bias[oc];
  // per (img,ch): 820 chunks x 8 bf16 = 6560 elements
  __hip_bfloat16* hb = hT + ((size_t)img * 32 + ch) * 6560 + icl;
#pragma unroll 1
  for (int r = rowg; r < 20; r += 4) {              // r = y
    float acc[20];
#pragma unroll
    for (int p = 0; p < 20; p++) acc[p] = bv;
#pragma unroll
    for (int ky = 0; ky < 9; ky++) {
      float xr[28];
      const float* xrow = &xs[(r + ky) * 28];
#pragma unroll
      for (int q = 0; q < 7; q++) ((float4*)xr)[q] = ((const float4*)xrow)[q];
      float wr[9];
#pragma unroll
      for (int i = 0; i < 9; i++) wr[i] = ws[ocl * 81 + ky * 9 + i];
#pragma unroll
      for (int kx = 0; kx < 9; kx++)
#pragma unroll
        for (int p = 0; p < 20; p++)
          acc[p] = fmaf(wr[kx], xr[p + kx], acc[p]);
    }
#pragma unroll
    for (int p = 0; p < 20; p++) {                  // p = x
      const float v = fmaxf(acc[p], 0.f);
      const __hip_bfloat16 hi = __float2bfloat16(v);
      const __hip_bfloat16 lo = __float2bfloat16(v - __bfloat162float(hi));
      __hip_bfloat16* dst = hb + (size_t)(p * 41 + r * 2) * 8;
      dst[0] = hi;
      dst[8] = lo;                                  // next chunk = half=1
    }
  }
}

// ==== weight repack: pw[oc][ic][81] -> wGp[step672][ocq4][oc64][32hi|32lo|8z]
__global__ __launch_bounds__(256) void k_wrep(const float* __restrict__ pw,
                                              __hip_bfloat16* __restrict__ wGp) {
  const int s = blockIdx.x >> 2, ocq = blockIdx.x & 3;   // s in [0,672)
  const int ch = s / 21, tq = s - ch * 21;
  __hip_bfloat16* outp = wGp + ((size_t)s * 4 + ocq) * 4608;
  const int t = threadIdx.x;
  for (int e = t; e < 2048; e += 256) {
    const int ocl = e >> 5, k = e & 31;
    const int tapl = k >> 3, icl = k & 7;
    const int tap = tq * 4 + tapl, ic = ch * 8 + icl;
    const int oc = ocq * 64 + ocl;
    const float v = (tap < 81) ? pw[((size_t)oc * 256 + ic) * 81 + tap] : 0.f;
    const __hip_bfloat16 hi = __float2bfloat16(v);
    const __hip_bfloat16 lo = __float2bfloat16(v - __bfloat162float(hi));
    outp[ocl * 72 + k] = hi;
    outp[ocl * 72 + 32 + k] = lo;
  }
  for (int e = t; e < 512; e += 256) {                   // zero the row pads
    const int ocl = e >> 3, j = e & 7;
    outp[ocl * 72 + 64 + j] = __float2bfloat16(0.f);
  }
}

// ====== conv2 MFMA: pq[kq][img][px36][oc256] partial over 16 ch each =======
// block 512 thr = 8 waves (mhalf x oc16-tile). 4 img, M=144 = 9 tiles.
// K-step 32 = 4 taps x 8 ic; 336 steps per kq. 3-pass split-bf16.
#define HT_B 52480              // 3280 chunks x 16B  (4 img x 820)
#define WS_B 9216               // 64 oc x 144B
#define PQ_F 2359296
__global__ __launch_bounds__(512) void k_conv2(
    const __hip_bfloat16* __restrict__ hTg,    // [chunk img][32ch][820ch][8]
    const __hip_bfloat16* __restrict__ wGp,    // [672][4ocq][4608B]
    float* __restrict__ pq, int c0) {
  __shared__ char smem[HT_B + 2 * WS_B];
  char* hT = smem;
  char* wS = smem + HT_B;
  const int bid = blockIdx.x;
  int ig, ocq, kq;
  if (gridDim.x == 512) {       // XCD swizzle: ocq sharers keep bid%8
    ig = (bid & 7) | (((bid >> 5) & 7) << 3);
    ocq = (bid >> 3) & 3;
    kq = bid >> 8;
  } else {
    ig = bid >> 3;
    ocq = (bid >> 1) & 3;
    kq = bid & 1;
  }
  const int t = threadIdx.x;
  const int w = t >> 6, lane = t & 63;
  const int lquad = lane >> 4, lrow = lane & 15;
  const int mhalf = w >> 2;
  const int nt = mhalf ? 4 : 5;
  const int mtb = mhalf ? 5 : 0;
  const int ocg = ocq * 64 + (w & 3) * 16 + lrow;
  int abase[5];
#pragma unroll
  for (int i = 0; i < 5; i++) {
    int m = (mtb + i) * 16 + lrow;
    if (i >= nt) m = 0;
    const int img = m / 36, px = m - img * 36;
    const int oy = px / 6, ox = px - oy * 6;
    abase[i] = img * 13120 + ox * 1312 + oy * 64;   // bytes in hT
  }
  f32x4 acc[5];
#pragma unroll
  for (int i = 0; i < 5; i++) acc[i] = (f32x4){0.f, 0.f, 0.f, 0.f};

  const char* hgc = (const char*)hTg;
  const char* wg = (const char*)wGp;
  {                                                 // pre-stage W local step 0
    const char* g = wg + ((size_t)(kq * 336) * 4 + ocq) * 4608;
    gl16(g + t * 16, wS + w * 1024);
    if (t < 64) gl16(g + 8192 + lane * 16, wS + 8192);
  }
  int step = 0;
#pragma unroll 1
  for (int chl = 0; chl < 16; chl++) {
    const int ch = kq * 16 + chl;
    const char* hch = hgc + ((size_t)(ig * 128) + ch) * 13120;
    // stage 3280 chunks (identity copy of global layout -> coalesced)
#pragma unroll
    for (int rr = 0; rr < 6; rr++) {
      const int idx = t + rr * 512;
      const int j = idx / 820, r = idx - j * 820;
      gl16(hch + (size_t)j * 419840 + r * 16, hT + rr * 8192 + w * 1024);
    }
    if (t < 208) {
      const int idx = 3072 + t;
      const int j = idx / 820, r = idx - j * 820;
      gl16(hch + (size_t)j * 419840 + r * 16, hT + 49152 + w * 1024);
    }
    __syncthreads();
#pragma unroll 1
    for (int tq = 0; tq < 21; tq++) {
      const int buf = step & 1;
      if (step + 1 < 336) {                         // prefetch next W slice
        const char* g = wg + ((size_t)(kq * 336 + step + 1) * 4 + ocq) * 4608;
        gl16(g + t * 16, wS + (buf ^ 1) * WS_B + w * 1024);
        if (t < 64) gl16(g + 8192 + lane * 16, wS + (buf ^ 1) * WS_B + 8192);
      }
      const char* wrow = wS + buf * WS_B + ((w & 3) * 16 + lrow) * 144 + lquad * 16;
      const bf16x8 bh = *(const bf16x8*)(wrow);
      const bf16x8 bl = *(const bf16x8*)(wrow + 64);
      const int tt = tq * 4 + lquad;                // this quad's tap
      const int ky = tt / 9, kx = tt - ky * 9;
      const int toff = kx * 656 + ky * 32;          // (kx*41 + ky*2) chunks
      bf16x8 ah[5], al[5];
#pragma unroll
      for (int i = 0; i < 5; i++) {
        const char* a = hT + abase[i] + toff;
        ah[i] = *(const bf16x8*)(a);
        al[i] = *(const bf16x8*)(a + 16);
      }
#pragma unroll
      for (int i = 0; i < 5; i++)
        if (i < nt) acc[i] = __builtin_amdgcn_mfma_f32_16x16x32_bf16(ah[i], bh, acc[i], 0, 0, 0);
#pragma unroll
      for (int i = 0; i < 5; i++)
        if (i < nt) acc[i] = __builtin_amdgcn_mfma_f32_16x16x32_bf16(ah[i], bl, acc[i], 0, 0, 0);
#pragma unroll
      for (int i = 0; i < 5; i++)
        if (i < nt) acc[i] = __builtin_amdgcn_mfma_f32_16x16x32_bf16(al[i], bh, acc[i], 0, 0, 0);
      step++;
      __syncthreads();
    }
  }
  float* pblk = pq + (size_t)kq * PQ_F;
#pragma unroll
  for (int i = 0; i < 5; i++) {
    if (i < nt) {
#pragma unroll
      for (int r = 0; r < 4; r++) {
        const int m = (mtb + i) * 16 + lquad * 4 + r;   // D row = quad*4+reg
        const int img = m / 36, px = m - img * 36;
        pblk[((size_t)(c0 + ig * 4 + img) * 36 + px) * 256 + ocg] = acc[i][r];
      }
    }
  }
}

// ===== squash: sum 2 partials + bias, [b][px][oc] -> u[b][i][8], squash ====
__global__ __launch_bounds__(256) void k_squash(const float* __restrict__ pq,
                                                const float* __restrict__ bias,
                                                float* __restrict__ u) {
  const int gid = blockIdx.x * 256 + threadIdx.x;   // b*1152 + i
  const int b = gid / 1152, i = gid - b * 1152;
  const int cp = i / 36, px = i - cp * 36;
  const float* pb = pq + ((size_t)b * 36 + px) * 256 + cp;
  float s[8];
#pragma unroll
  for (int d = 0; d < 8; d++)
    s[d] = pb[d * 32] + pb[(size_t)PQ_F + d * 32] + bias[cp + d * 32];
  float sq = 0.f;
#pragma unroll
  for (int d = 0; d < 8; d++) sq = fmaf(s[d], s[d], sq);
  const float scale = sq / ((1.f + sq) * sqrtf(sq));
  float o[8];
#pragma unroll
  for (int d = 0; d < 8; d++) o[d] = s[d] * scale;
  float* ub = u + (size_t)gid * 8;
  ((float4*)ub)[0] = ((float4*)o)[0];
  ((float4*)ub)[1] = ((float4*)o)[1];
}

// ======================= routing by agreement (per o,b block) ==============
__device__ __forceinline__ float wsum(float v) {
#pragma unroll
  for (int o = 32; o > 0; o >>= 1) v += __shfl_xor(v, o, 64);
  return v;
}
__device__ __forceinline__ float wmaxr(float v) {
#pragma unroll
  for (int o = 32; o > 0; o >>= 1) v = fmaxf(v, __shfl_xor(v, o, 64));
  return v;
}

__global__ __launch_bounds__(256) void k_route(const float* __restrict__ u,
                                               const float* __restrict__ rw,
                                               float* __restrict__ vecs) {
  const int o = blockIdx.x >> 8, b = blockIdx.x & 255;
  __shared__ float us[9216];
  __shared__ float red[4 * 17];
  __shared__ float redm[4];
  const int t = threadIdx.x;
  const int wave = t >> 6, lane = t & 63;
  {
    const float4* ub = (const float4*)(u + (size_t)b * 9216);
    for (int i = t; i < 2304; i += 256) ((float4*)us)[i] = ub[i];
  }
  __syncthreads();
  float pri[5][16];
  const float* rwo = rw + (size_t)o * 147456;
#pragma unroll
  for (int ci = 0; ci < 5; ci++) {
    const bool valid = (ci < 4) || (t < 128);
    const int i = valid ? (t + ci * 256) : 0;
    const float* rwi = rwo + (size_t)i * 128;
    float a[16];
#pragma unroll
    for (int d = 0; d < 16; d++) a[d] = 0.f;
#pragma unroll
    for (int c = 0; c < 8; c++) {
      const float uv = us[i * 8 + c];
      const float4* r4 = (const float4*)(rwi + c * 16);
      const float4 p0 = r4[0], p1 = r4[1], p2 = r4[2], p3 = r4[3];
      a[0] = fmaf(uv, p0.x, a[0]);  a[1] = fmaf(uv, p0.y, a[1]);
      a[2] = fmaf(uv, p0.z, a[2]);  a[3] = fmaf(uv, p0.w, a[3]);
      a[4] = fmaf(uv, p1.x, a[4]);  a[5] = fmaf(uv, p1.y, a[5]);
      a[6] = fmaf(uv, p1.z, a[6]);  a[7] = fmaf(uv, p1.w, a[7]);
      a[8] = fmaf(uv, p2.x, a[8]);  a[9] = fmaf(uv, p2.y, a[9]);
      a[10] = fmaf(uv, p2.z, a[10]); a[11] = fmaf(uv, p2.w, a[11]);
      a[12] = fmaf(uv, p3.x, a[12]); a[13] = fmaf(uv, p3.y, a[13]);
      a[14] = fmaf(uv, p3.z, a[14]); a[15] = fmaf(uv, p3.w, a[15]);
    }
#pragma unroll
    for (int d = 0; d < 16; d++) pri[ci][d] = valid ? a[d] : 0.f;
  }
  float l[5];
#pragma unroll
  for (int ci = 0; ci < 5; ci++)
    l[ci] = ((ci < 4) || (t < 128)) ? 0.f : -1e30f;
  float v[16];
#pragma unroll 1
  for (int it = 0; it < 3; it++) {
    float m = l[0];
#pragma unroll
    for (int ci = 1; ci < 5; ci++) m = fmaxf(m, l[ci]);
    m = wmaxr(m);
    if (lane == 0) redm[wave] = m;
    __syncthreads();
    m = fmaxf(fmaxf(redm[0], redm[1]), fmaxf(redm[2], redm[3]));
    float Z = 0.f, S[16];
#pragma unroll
    for (int d = 0; d < 16; d++) S[d] = 0.f;
#pragma unroll
    for (int ci = 0; ci < 5; ci++) {
      const float e = expf(l[ci] - m);
      Z += e;
#pragma unroll
      for (int d = 0; d < 16; d++) S[d] = fmaf(e, pri[ci][d], S[d]);
    }
    Z = wsum(Z);
#pragma unroll
    for (int d = 0; d < 16; d++) S[d] = wsum(S[d]);
    __syncthreads();
    if (lane == 0) {
      red[wave * 17] = Z;
#pragma unroll
      for (int d = 0; d < 16; d++) red[wave * 17 + 1 + d] = S[d];
    }
    __syncthreads();
    const float Zt = red[0] + red[17] + red[34] + red[51];
    float sv[16], sq = 0.f;
#pragma unroll
    for (int d = 0; d < 16; d++) {
      const float sd = (red[1 + d] + red[18 + d] + red[35 + d] + red[52 + d]) / Zt;
      sv[d] = sd;
      sq = fmaf(sd, sd, sq);
    }
    const float scale = sq / ((1.f + sq) * sqrtf(sq));
#pragma unroll
    for (int d = 0; d < 16; d++) v[d] = scale * sv[d];
    if (it < 2) {
#pragma unroll
      for (int ci = 0; ci < 5; ci++) {
        float dot = 0.f;
#pragma unroll
        for (int d = 0; d < 16; d++) dot = fmaf(pri[ci][d], v[d], dot);
        l[ci] += dot;
      }
    }
  }
  if (t == 0) {
    float* vb = vecs + ((size_t)b * 10 + o) * 16;
#pragma unroll
    for (int d = 0; d < 16; d++) vb[d] = v[d];
  }
}

// =============== classes softmax + argmax + selected-vector ================
__global__ __launch_bounds__(64) void k_cls(const float* __restrict__ vecs,
                                            float* __restrict__ out,
                                            float* __restrict__ selvec,
                                            int* __restrict__ amv) {
  const int b = blockIdx.x * 64 + threadIdx.x;
  const float* vb = vecs + (size_t)b * 160;
  float n[10];
#pragma unroll
  for (int o = 0; o < 10; o++) {
    float sq = 0.f;
#pragma unroll
    for (int d = 0; d < 16; d++) { const float xv = vb[o * 16 + d]; sq = fmaf(xv, xv, sq); }
    n[o] = sqrtf(sq);
  }
  float m = n[0];
#pragma unroll
  for (int o = 1; o < 10; o++) m = fmaxf(m, n[o]);
  float e[10], Z = 0.f;
#pragma unroll
  for (int o = 0; o < 10; o++) { e[o] = expf(n[o] - m); Z += e[o]; }
  const float inv = 1.f / Z;
  float cls[10];
#pragma unroll
  for (int o = 0; o < 10; o++) {
    cls[o] = e[o] * inv;
    out[(size_t)b * 10 + o] = cls[o];
  }
  int am = 0;
  float best = cls[0];
#pragma unroll
  for (int o = 1; o < 10; o++)
    if (cls[o] > best) { best = cls[o]; am = o; }
  amv[b] = am;
#pragma unroll
  for (int d = 0; d < 16; d++) selvec[(size_t)b * 16 + d] = vb[am * 16 + d];
}

// ============================= decoder =====================================
__global__ __launch_bounds__(512) void k_dec1(const float* __restrict__ selvec,
                                              const int* __restrict__ amv,
                                              const float* __restrict__ w1,
                                              const float* __restrict__ b1,
                                              float* __restrict__ h1) {
  const int b = blockIdx.x, t = threadIdx.x;
  __shared__ float sv[16];
  __shared__ int ams;
  if (t < 16) sv[t] = selvec[(size_t)b * 16 + t];
  if (t == 0) ams = amv[b];
  __syncthreads();
  const float* wrow = w1 + (size_t)ams * 16 * 512;
  float acc = b1[t];
#pragma unroll
  for (int d = 0; d < 16; d++) acc = fmaf(sv[d], wrow[d * 512 + t], acc);
  h1[(size_t)b * 512 + t] = fmaxf(acc, 0.f);
}

__global__ __launch_bounds__(128) void k_dec2(const float* __restrict__ h1,
                                              const float* __restrict__ w2,
                                              const float* __restrict__ b2,
                                              float* __restrict__ h2) {
  const int nc = blockIdx.x >> 5, bg = blockIdx.x & 31;
  const int t = threadIdx.x;
  const int n = nc * 128 + t;
  const int bs = bg * 8;
  __shared__ float h1s[8 * 512];
  {
    const float4* src = (const float4*)(h1 + (size_t)bs * 512);
    for (int i = t; i < 1024; i += 128) ((float4*)h1s)[i] = src[i];
  }
  __syncthreads();
  float acc[8];
  const float bb = b2[n];
#pragma unroll
  for (int j = 0; j < 8; j++) acc[j] = bb;
#pragma unroll 1
  for (int k = 0; k < 512; k += 4) {
    float wq[4];
#pragma unroll
    for (int q = 0; q < 4; q++) wq[q] = w2[(size_t)(k + q) * 1024 + n];
#pragma unroll
    for (int j = 0; j < 8; j++) {
      const float4 hv = *(const float4*)&h1s[j * 512 + k];
      acc[j] = fmaf(hv.x, wq[0], acc[j]);
      acc[j] = fmaf(hv.y, wq[1], acc[j]);
      acc[j] = fmaf(hv.z, wq[2], acc[j]);
      acc[j] = fmaf(hv.w, wq[3], acc[j]);
    }
  }
#pragma unroll
  for (int j = 0; j < 8; j++) h2[(size_t)(bs + j) * 1024 + n] = fmaxf(acc[j], 0.f);
}

__global__ __launch_bounds__(128) void k_dec3(const float* __restrict__ h2,
                                              const float* __restrict__ w3,
                                              const float* __restrict__ b3,
                                              float* __restrict__ out) {
  const int nc = blockIdx.x >> 5, bg = blockIdx.x & 31;   // grid 7*32
  const int t = threadIdx.x;
  const int bs = bg * 8;
  __shared__ float h2s[8 * 1024];
  {
    const float4* src = (const float4*)(h2 + (size_t)bs * 1024);
    for (int i = t; i < 2048; i += 128) ((float4*)h2s)[i] = src[i];
  }
  __syncthreads();
  if (t >= 112) return;
  const int n = nc * 112 + t;
  float acc[8];
  const float bb = b3[n];
#pragma unroll
  for (int j = 0; j < 8; j++) acc[j] = bb;
#pragma unroll 1
  for (int k = 0; k < 1024; k += 4) {
    float wq[4];
#pragma unroll
    for (int q = 0; q < 4; q++) wq[q] = w3[(size_t)(k + q) * 784 + n];
#pragma unroll
    for (int j = 0; j < 8; j++) {
      const float4 hv = *(const float4*)&h2s[j * 1024 + k];
      acc[j] = fmaf(hv.x, wq[0], acc[j]);
      acc[j] = fmaf(hv.y, wq[1], acc[j]);
      acc[j] = fmaf(hv.z, wq[2], acc[j]);
      acc[j] = fmaf(hv.w, wq[3], acc[j]);
    }
  }
#pragma unroll
  for (int j = 0; j < 8; j++)
    out[(size_t)(bs + j) * 784 + n] = 1.f / (1.f + expf(-acc[j]));
}

// ============================= launcher ====================================
extern "C" void kernel_launch(void* const* d_in, const int* in_sizes, int n_in,
                              void* d_out, int out_size, void* d_ws, size_t ws_size,
                              hipStream_t stream) {
  const float* x   = (const float*)d_in[0];
  const float* c1w = (const float*)d_in[1];
  const float* c1b = (const float*)d_in[2];
  const float* pw  = (const float*)d_in[3];
  const float* pb  = (const float*)d_in[4];
  const float* rw  = (const float*)d_in[5];
  const float* w1  = (const float*)d_in[6];
  const float* b1  = (const float*)d_in[7];
  const float* w2  = (const float*)d_in[8];
  const float* b2  = (const float*)d_in[9];
  const float* w3  = (const float*)d_in[10];
  const float* b3  = (const float*)d_in[11];
  float* out = (float*)d_out;
  float* ws = (float*)d_ws;

  const size_t WGP_F = (size_t)672 * 4 * 4608 / 4;     // wGp bytes/4 = floats
  const size_t U_F = 2359296;
  const size_t SMALL_F = 40960 + 4096 + 256 + 131072 + 262144;
  const size_t fixed_f = WGP_F + 2 * PQ_F + U_F + SMALL_F;
  int chunk = 256;                                     // imgs per pipeline iter
  // hTgc floats per img: 32ch * 820 chunks * 16B / 4 = 104960
  while (chunk > 8 && (fixed_f + (size_t)chunk * 104960) * 4 > ws_size) chunk >>= 1;

  __hip_bfloat16* wGp  = (__hip_bfloat16*)ws;
  __hip_bfloat16* hTgc = (__hip_bfloat16*)(ws + WGP_F);
  float* pq   = ws + WGP_F + (size_t)chunk * 104960;   // 2 partial buffers
  float* u    = pq + 2 * PQ_F;
  float* vecs = u + U_F;
  float* sel  = vecs + 40960;
  int*   amv  = (int*)(sel + 4096);
  float* h1   = sel + 4096 + 256;
  float* h2   = h1 + 131072;

  k_wrep<<<dim3(2688), dim3(256), 0, stream>>>(pw, wGp);
  for (int c0 = 0; c0 < 256; c0 += chunk) {
    k_conv1<<<dim3(chunk * 4), dim3(256), 0, stream>>>(x + (size_t)c0 * 784, c1w, c1b, hTgc);
    k_conv2<<<dim3((chunk / 4) * 8), dim3(512), 0, stream>>>(hTgc, wGp, pq, c0);
  }
  k_squash<<<dim3(1152), dim3(256), 0, stream>>>(pq, pb, u);
  k_route<<<dim3(2560), dim3(256), 0, stream>>>(u, rw, vecs);
  k_cls<<<dim3(4), dim3(64), 0, stream>>>(vecs, out, sel, amv);
  k_dec1<<<dim3(256), dim3(512), 0, stream>>>(sel, amv, w1, b1, h1);
  k_dec2<<<dim3(256), dim3(128), 0, stream>>>(h1, w2, b2, h2);
  k_dec3<<<dim3(224), dim3(128), 0, stream>>>(h2, w3, b3, out + 2560);
}

// Round 7
// 867.766 us; speedup vs baseline: 4.6372x; 1.0282x over previous
//
#include <hip/hip_runtime.h>
#include <hip/hip_bf16.h>
#include <math.h>

// ---------------------------------------------------------------------------
// CapsNet forward. R7:
//  - conv2: W fragments loaded straight to VGPRs (per-lane, 1-step prefetch)
//    -> K-loop has NO barriers (R6 had 672 barrier-drains/block = m97-style
//    vmcnt(0) stall, MfmaUtil capped at 42%). Only 2 barriers per ch for hT.
//  - dec2/dec3: LDS-staged 32-k weight tiles (they were 1-wave/SIMD
//    L2-latency-bound: ~45/~90 us).
// ---------------------------------------------------------------------------

typedef __attribute__((ext_vector_type(8))) short bf16x8;
typedef __attribute__((ext_vector_type(4))) float f32x4;

__device__ __forceinline__ void gl16(const void* g, void* l) {
  __builtin_amdgcn_global_load_lds((const __attribute__((address_space(1))) void*)g,
                                   (__attribute__((address_space(3))) void*)l,
                                   16, 0, 0);
}

// ==== conv1: [B,1,28,28] -> hTg[img][ch][(x*41+y*2+half) chunk][8 bf16] ====
__global__ __launch_bounds__(256) void k_conv1(const float* __restrict__ x,
                                               const float* __restrict__ w,
                                               const float* __restrict__ bias,
                                               __hip_bfloat16* __restrict__ hT) {
  const int bid = blockIdx.x;
  const int img = bid >> 2, ocq = bid & 3;          // 64 oc per block
  __shared__ float xs[784];
  __shared__ float ws[64 * 81];
  const int t = threadIdx.x;
  const float4* xg = (const float4*)(x + (size_t)img * 784);
  if (t < 196) ((float4*)xs)[t] = xg[t];
  const float4* wg = (const float4*)(w + (size_t)ocq * 64 * 81);
  for (int i = t; i < 1296; i += 256) ((float4*)ws)[i] = wg[i];
  __syncthreads();
  const int ocl = t & 63, rowg = t >> 6;            // wave-uniform row
  const int oc = ocq * 64 + ocl;
  const int ch = oc >> 3, icl = oc & 7;
  const float bv = bias[oc];
  __hip_bfloat16* hb = hT + ((size_t)img * 32 + ch) * 6560 + icl;
#pragma unroll 1
  for (int r = rowg; r < 20; r += 4) {              // r = y
    float acc[20];
#pragma unroll
    for (int p = 0; p < 20; p++) acc[p] = bv;
#pragma unroll
    for (int ky = 0; ky < 9; ky++) {
      float xr[28];
      const float* xrow = &xs[(r + ky) * 28];
#pragma unroll
      for (int q = 0; q < 7; q++) ((float4*)xr)[q] = ((const float4*)xrow)[q];
      float wr[9];
#pragma unroll
      for (int i = 0; i < 9; i++) wr[i] = ws[ocl * 81 + ky * 9 + i];
#pragma unroll
      for (int kx = 0; kx < 9; kx++)
#pragma unroll
        for (int p = 0; p < 20; p++)
          acc[p] = fmaf(wr[kx], xr[p + kx], acc[p]);
    }
#pragma unroll
    for (int p = 0; p < 20; p++) {                  // p = x
      const float v = fmaxf(acc[p], 0.f);
      const __hip_bfloat16 hi = __float2bfloat16(v);
      const __hip_bfloat16 lo = __float2bfloat16(v - __bfloat162float(hi));
      __hip_bfloat16* dst = hb + (size_t)(p * 41 + r * 2) * 8;
      dst[0] = hi;
      dst[8] = lo;
    }
  }
}

// ==== weight repack: pw[oc][ic][81] -> wGp[step672][ocq4][oc64][32hi|32lo|8z]
__global__ __launch_bounds__(256) void k_wrep(const float* __restrict__ pw,
                                              __hip_bfloat16* __restrict__ wGp) {
  const int s = blockIdx.x >> 2, ocq = blockIdx.x & 3;   // s in [0,672)
  const int ch = s / 21, tq = s - ch * 21;
  __hip_bfloat16* outp = wGp + ((size_t)s * 4 + ocq) * 4608;
  const int t = threadIdx.x;
  for (int e = t; e < 2048; e += 256) {
    const int ocl = e >> 5, k = e & 31;
    const int tapl = k >> 3, icl = k & 7;
    const int tap = tq * 4 + tapl, ic = ch * 8 + icl;
    const int oc = ocq * 64 + ocl;
    const float v = (tap < 81) ? pw[((size_t)oc * 256 + ic) * 81 + tap] : 0.f;
    const __hip_bfloat16 hi = __float2bfloat16(v);
    const __hip_bfloat16 lo = __float2bfloat16(v - __bfloat162float(hi));
    outp[ocl * 72 + k] = hi;
    outp[ocl * 72 + 32 + k] = lo;
  }
  for (int e = t; e < 512; e += 256) {                   // zero the row pads
    const int ocl = e >> 3, j = e & 7;
    outp[ocl * 72 + 64 + j] = __float2bfloat16(0.f);
  }
}

// ====== conv2 MFMA: pq[kq][img][px36][oc256] partial over 16 ch each =======
// block 512 thr = 8 waves. W fragments per-lane from global (VGPR), 1-step
// prefetch; barrier-free K-loop. hT staged per ch via global_load_lds.
#define HT_B 52480              // 3280 chunks x 16B  (4 img x 820)
#define PQ_F 2359296
__global__ __launch_bounds__(512) void k_conv2(
    const __hip_bfloat16* __restrict__ hTg,    // [chunk img][32ch][820ch][8]
    const __hip_bfloat16* __restrict__ wGp,    // [672][4ocq][4608B] (+1 pad step)
    float* __restrict__ pq, int c0) {
  __shared__ char hT[HT_B];
  const int bid = blockIdx.x;
  int ig, ocq, kq;
  if (gridDim.x == 512) {       // XCD swizzle: ocq sharers keep bid%8
    ig = (bid & 7) | (((bid >> 5) & 7) << 3);
    ocq = (bid >> 3) & 3;
    kq = bid >> 8;
  } else {
    ig = bid >> 3;
    ocq = (bid >> 1) & 3;
    kq = bid & 1;
  }
  const int t = threadIdx.x;
  const int w = t >> 6, lane = t & 63;
  const int lquad = lane >> 4, lrow = lane & 15;
  const int mhalf = w >> 2;
  const int nt = mhalf ? 4 : 5;
  const int mtb = mhalf ? 5 : 0;
  const int ocg = ocq * 64 + (w & 3) * 16 + lrow;
  int abase[5];
#pragma unroll
  for (int i = 0; i < 5; i++) {
    int m = (mtb + i) * 16 + lrow;
    if (i >= nt) m = 0;
    const int img = m / 36, px = m - img * 36;
    const int oy = px / 6, ox = px - oy * 6;
    abase[i] = img * 13120 + ox * 1312 + oy * 64;   // bytes in hT
  }
  f32x4 acc[5];
#pragma unroll
  for (int i = 0; i < 5; i++) acc[i] = (f32x4){0.f, 0.f, 0.f, 0.f};

  const char* hgc = (const char*)hTg;
  // per-lane W pointer: lane owns (oc row = (w&3)*16+lrow, k-quad = lquad)
  const char* wp = (const char*)wGp + ((size_t)(kq * 336) * 4 + ocq) * 4608 +
                   ((w & 3) * 16 + lrow) * 144 + lquad * 16;
  bf16x8 bh = *(const bf16x8*)wp;
  bf16x8 bl = *(const bf16x8*)(wp + 64);
  wp += 18432;
#pragma unroll 1
  for (int chl = 0; chl < 16; chl++) {
    const int ch = kq * 16 + chl;
    const char* hch = hgc + ((size_t)(ig * 128) + ch) * 13120;
#pragma unroll
    for (int rr = 0; rr < 6; rr++) {
      const int idx = t + rr * 512;
      const int j = idx / 820, r = idx - j * 820;
      gl16(hch + (size_t)j * 419840 + r * 16, hT + rr * 8192 + w * 1024);
    }
    if (t < 208) {
      const int idx = 3072 + t;
      const int j = idx / 820, r = idx - j * 820;
      gl16(hch + (size_t)j * 419840 + r * 16, hT + 49152 + w * 1024);
    }
    __syncthreads();
#pragma unroll 1
    for (int tq = 0; tq < 21; tq++) {
      const bf16x8 nh = *(const bf16x8*)wp;         // prefetch next step's W
      const bf16x8 nl = *(const bf16x8*)(wp + 64);  // (buffer padded 1 step)
      wp += 18432;
      const int tt = tq * 4 + lquad;                // this quad's tap
      const int ky = tt / 9, kx = tt - ky * 9;
      const int toff = kx * 656 + ky * 32;          // (kx*41 + ky*2) chunks
      bf16x8 ah[5];
#pragma unroll
      for (int i = 0; i < 5; i++)
        ah[i] = *(const bf16x8*)(hT + abase[i] + toff);
#pragma unroll
      for (int i = 0; i < 5; i++)
        if (i < nt) acc[i] = __builtin_amdgcn_mfma_f32_16x16x32_bf16(ah[i], bh, acc[i], 0, 0, 0);
#pragma unroll
      for (int i = 0; i < 5; i++)
        if (i < nt) acc[i] = __builtin_amdgcn_mfma_f32_16x16x32_bf16(ah[i], bl, acc[i], 0, 0, 0);
      bf16x8 al[5];
#pragma unroll
      for (int i = 0; i < 5; i++)
        al[i] = *(const bf16x8*)(hT + abase[i] + toff + 16);
#pragma unroll
      for (int i = 0; i < 5; i++)
        if (i < nt) acc[i] = __builtin_amdgcn_mfma_f32_16x16x32_bf16(al[i], bh, acc[i], 0, 0, 0);
      bh = nh;
      bl = nl;
    }
    __syncthreads();                                // hT reuse fence
  }
  float* pblk = pq + (size_t)kq * PQ_F;
#pragma unroll
  for (int i = 0; i < 5; i++) {
    if (i < nt) {
#pragma unroll
      for (int r = 0; r < 4; r++) {
        const int m = (mtb + i) * 16 + lquad * 4 + r;   // D row = quad*4+reg
        const int img = m / 36, px = m - img * 36;
        pblk[((size_t)(c0 + ig * 4 + img) * 36 + px) * 256 + ocg] = acc[i][r];
      }
    }
  }
}

// ===== squash: sum 2 partials + bias, [b][px][oc] -> u[b][i][8], squash ====
__global__ __launch_bounds__(256) void k_squash(const float* __restrict__ pq,
                                                const float* __restrict__ bias,
                                                float* __restrict__ u) {
  const int gid = blockIdx.x * 256 + threadIdx.x;   // b*1152 + i
  const int b = gid / 1152, i = gid - b * 1152;
  const int cp = i / 36, px = i - cp * 36;
  const float* pb = pq + ((size_t)b * 36 + px) * 256 + cp;
  float s[8];
#pragma unroll
  for (int d = 0; d < 8; d++)
    s[d] = pb[d * 32] + pb[(size_t)PQ_F + d * 32] + bias[cp + d * 32];
  float sq = 0.f;
#pragma unroll
  for (int d = 0; d < 8; d++) sq = fmaf(s[d], s[d], sq);
  const float scale = sq / ((1.f + sq) * sqrtf(sq));
  float o[8];
#pragma unroll
  for (int d = 0; d < 8; d++) o[d] = s[d] * scale;
  float* ub = u + (size_t)gid * 8;
  ((float4*)ub)[0] = ((float4*)o)[0];
  ((float4*)ub)[1] = ((float4*)o)[1];
}

// ======================= routing by agreement (per o,b block) ==============
__device__ __forceinline__ float wsum(float v) {
#pragma unroll
  for (int o = 32; o > 0; o >>= 1) v += __shfl_xor(v, o, 64);
  return v;
}
__device__ __forceinline__ float wmaxr(float v) {
#pragma unroll
  for (int o = 32; o > 0; o >>= 1) v = fmaxf(v, __shfl_xor(v, o, 64));
  return v;
}

__global__ __launch_bounds__(256) void k_route(const float* __restrict__ u,
                                               const float* __restrict__ rw,
                                               float* __restrict__ vecs) {
  const int o = blockIdx.x >> 8, b = blockIdx.x & 255;
  __shared__ float us[9216];
  __shared__ float red[4 * 17];
  __shared__ float redm[4];
  const int t = threadIdx.x;
  const int wave = t >> 6, lane = t & 63;
  {
    const float4* ub = (const float4*)(u + (size_t)b * 9216);
    for (int i = t; i < 2304; i += 256) ((float4*)us)[i] = ub[i];
  }
  __syncthreads();
  float pri[5][16];
  const float* rwo = rw + (size_t)o * 147456;
#pragma unroll
  for (int ci = 0; ci < 5; ci++) {
    const bool valid = (ci < 4) || (t < 128);
    const int i = valid ? (t + ci * 256) : 0;
    const float* rwi = rwo + (size_t)i * 128;
    float a[16];
#pragma unroll
    for (int d = 0; d < 16; d++) a[d] = 0.f;
#pragma unroll
    for (int c = 0; c < 8; c++) {
      const float uv = us[i * 8 + c];
      const float4* r4 = (const float4*)(rwi + c * 16);
      const float4 p0 = r4[0], p1 = r4[1], p2 = r4[2], p3 = r4[3];
      a[0] = fmaf(uv, p0.x, a[0]);  a[1] = fmaf(uv, p0.y, a[1]);
      a[2] = fmaf(uv, p0.z, a[2]);  a[3] = fmaf(uv, p0.w, a[3]);
      a[4] = fmaf(uv, p1.x, a[4]);  a[5] = fmaf(uv, p1.y, a[5]);
      a[6] = fmaf(uv, p1.z, a[6]);  a[7] = fmaf(uv, p1.w, a[7]);
      a[8] = fmaf(uv, p2.x, a[8]);  a[9] = fmaf(uv, p2.y, a[9]);
      a[10] = fmaf(uv, p2.z, a[10]); a[11] = fmaf(uv, p2.w, a[11]);
      a[12] = fmaf(uv, p3.x, a[12]); a[13] = fmaf(uv, p3.y, a[13]);
      a[14] = fmaf(uv, p3.z, a[14]); a[15] = fmaf(uv, p3.w, a[15]);
    }
#pragma unroll
    for (int d = 0; d < 16; d++) pri[ci][d] = valid ? a[d] : 0.f;
  }
  float l[5];
#pragma unroll
  for (int ci = 0; ci < 5; ci++)
    l[ci] = ((ci < 4) || (t < 128)) ? 0.f : -1e30f;
  float v[16];
#pragma unroll 1
  for (int it = 0; it < 3; it++) {
    float m = l[0];
#pragma unroll
    for (int ci = 1; ci < 5; ci++) m = fmaxf(m, l[ci]);
    m = wmaxr(m);
    if (lane == 0) redm[wave] = m;
    __syncthreads();
    m = fmaxf(fmaxf(redm[0], redm[1]), fmaxf(redm[2], redm[3]));
    float Z = 0.f, S[16];
#pragma unroll
    for (int d = 0; d < 16; d++) S[d] = 0.f;
#pragma unroll
    for (int ci = 0; ci < 5; ci++) {
      const float e = expf(l[ci] - m);
      Z += e;
#pragma unroll
      for (int d = 0; d < 16; d++) S[d] = fmaf(e, pri[ci][d], S[d]);
    }
    Z = wsum(Z);
#pragma unroll
    for (int d = 0; d < 16; d++) S[d] = wsum(S[d]);
    __syncthreads();
    if (lane == 0) {
      red[wave * 17] = Z;
#pragma unroll
      for (int d = 0; d < 16; d++) red[wave * 17 + 1 + d] = S[d];
    }
    __syncthreads();
    const float Zt = red[0] + red[17] + red[34] + red[51];
    float sv[16], sq = 0.f;
#pragma unroll
    for (int d = 0; d < 16; d++) {
      const float sd = (red[1 + d] + red[18 + d] + red[35 + d] + red[52 + d]) / Zt;
      sv[d] = sd;
      sq = fmaf(sd, sd, sq);
    }
    const float scale = sq / ((1.f + sq) * sqrtf(sq));
#pragma unroll
    for (int d = 0; d < 16; d++) v[d] = scale * sv[d];
    if (it < 2) {
#pragma unroll
      for (int ci = 0; ci < 5; ci++) {
        float dot = 0.f;
#pragma unroll
        for (int d = 0; d < 16; d++) dot = fmaf(pri[ci][d], v[d], dot);
        l[ci] += dot;
      }
    }
  }
  if (t == 0) {
    float* vb = vecs + ((size_t)b * 10 + o) * 16;
#pragma unroll
    for (int d = 0; d < 16; d++) vb[d] = v[d];
  }
}

// =============== classes softmax + argmax + selected-vector ================
__global__ __launch_bounds__(64) void k_cls(const float* __restrict__ vecs,
                                            float* __restrict__ out,
                                            float* __restrict__ selvec,
                                            int* __restrict__ amv) {
  const int b = blockIdx.x * 64 + threadIdx.x;
  const float* vb = vecs + (size_t)b * 160;
  float n[10];
#pragma unroll
  for (int o = 0; o < 10; o++) {
    float sq = 0.f;
#pragma unroll
    for (int d = 0; d < 16; d++) { const float xv = vb[o * 16 + d]; sq = fmaf(xv, xv, sq); }
    n[o] = sqrtf(sq);
  }
  float m = n[0];
#pragma unroll
  for (int o = 1; o < 10; o++) m = fmaxf(m, n[o]);
  float e[10], Z = 0.f;
#pragma unroll
  for (int o = 0; o < 10; o++) { e[o] = expf(n[o] - m); Z += e[o]; }
  const float inv = 1.f / Z;
  float cls[10];
#pragma unroll
  for (int o = 0; o < 10; o++) {
    cls[o] = e[o] * inv;
    out[(size_t)b * 10 + o] = cls[o];
  }
  int am = 0;
  float best = cls[0];
#pragma unroll
  for (int o = 1; o < 10; o++)
    if (cls[o] > best) { best = cls[o]; am = o; }
  amv[b] = am;
#pragma unroll
  for (int d = 0; d < 16; d++) selvec[(size_t)b * 16 + d] = vb[am * 16 + d];
}

// ============================= decoder =====================================
__global__ __launch_bounds__(512) void k_dec1(const float* __restrict__ selvec,
                                              const int* __restrict__ amv,
                                              const float* __restrict__ w1,
                                              const float* __restrict__ b1,
                                              float* __restrict__ h1) {
  const int b = blockIdx.x, t = threadIdx.x;
  __shared__ float sv[16];
  __shared__ int ams;
  if (t < 16) sv[t] = selvec[(size_t)b * 16 + t];
  if (t == 0) ams = amv[b];
  __syncthreads();
  const float* wrow = w1 + (size_t)ams * 16 * 512;
  float acc = b1[t];
#pragma unroll
  for (int d = 0; d < 16; d++) acc = fmaf(sv[d], wrow[d * 512 + t], acc);
  h1[(size_t)b * 512 + t] = fmaxf(acc, 0.f);
}

// dec2: 8 imgs x 128 n per block; w2 staged in 32-k LDS tiles (16 stages).
__global__ __launch_bounds__(128) void k_dec2(const float* __restrict__ h1,
                                              const float* __restrict__ w2,
                                              const float* __restrict__ b2,
                                              float* __restrict__ h2) {
  const int nc = blockIdx.x >> 5, bg = blockIdx.x & 31;
  const int t = threadIdx.x;
  const int n = nc * 128 + t;
  const int bs = bg * 8;
  __shared__ float h1s[8 * 512];
  __shared__ float wts[32 * 128];
  {
    const float4* src = (const float4*)(h1 + (size_t)bs * 512);
    for (int i = t; i < 1024; i += 128) ((float4*)h1s)[i] = src[i];
  }
  float acc[8];
  const float bb = b2[n];
#pragma unroll
  for (int j = 0; j < 8; j++) acc[j] = bb;
#pragma unroll 1
  for (int kt = 0; kt < 16; kt++) {
    __syncthreads();                                // prev tile consumed
#pragma unroll
    for (int r = 0; r < 32; r++)                    // coalesced 512B rows
      wts[r * 128 + t] = w2[(size_t)(kt * 32 + r) * 1024 + n];
    __syncthreads();
#pragma unroll
    for (int k4 = 0; k4 < 8; k4++) {
      float wq[4];
#pragma unroll
      for (int q = 0; q < 4; q++) wq[q] = wts[(k4 * 4 + q) * 128 + t];
#pragma unroll
      for (int j = 0; j < 8; j++) {
        const float4 hv = *(const float4*)&h1s[j * 512 + kt * 32 + k4 * 4];
        acc[j] = fmaf(hv.x, wq[0], acc[j]);
        acc[j] = fmaf(hv.y, wq[1], acc[j]);
        acc[j] = fmaf(hv.z, wq[2], acc[j]);
        acc[j] = fmaf(hv.w, wq[3], acc[j]);
      }
    }
  }
#pragma unroll
  for (int j = 0; j < 8; j++) h2[(size_t)(bs + j) * 1024 + n] = fmaxf(acc[j], 0.f);
}

// dec3: 8 imgs x 112 n per block; w3 staged in 32-k LDS tiles (32 stages).
__global__ __launch_bounds__(128) void k_dec3(const float* __restrict__ h2,
                                              const float* __restrict__ w3,
                                              const float* __restrict__ b3,
                                              float* __restrict__ out) {
  const int nc = blockIdx.x >> 5, bg = blockIdx.x & 31;   // grid 7*32
  const int t = threadIdx.x;
  const int bs = bg * 8;
  __shared__ float h2s[8 * 1024];
  __shared__ float wts[32 * 112];
  {
    const float4* src = (const float4*)(h2 + (size_t)bs * 1024);
    for (int i = t; i < 2048; i += 128) ((float4*)h2s)[i] = src[i];
  }
  const int n = nc * 112 + (t < 112 ? t : 0);
  float acc[8];
  const float bb = b3[n];
#pragma unroll
  for (int j = 0; j < 8; j++) acc[j] = bb;
#pragma unroll 1
  for (int kt = 0; kt < 32; kt++) {
    __syncthreads();
#pragma unroll
    for (int r = 0; r < 32; r++)
      if (t < 112) wts[r * 112 + t] = w3[(size_t)(kt * 32 + r) * 784 + n];
    __syncthreads();
    if (t < 112) {
#pragma unroll
      for (int k4 = 0; k4 < 8; k4++) {
        float wq[4];
#pragma unroll
        for (int q = 0; q < 4; q++) wq[q] = wts[(k4 * 4 + q) * 112 + t];
#pragma unroll
        for (int j = 0; j < 8; j++) {
          const float4 hv = *(const float4*)&h2s[j * 1024 + kt * 32 + k4 * 4];
          acc[j] = fmaf(hv.x, wq[0], acc[j]);
          acc[j] = fmaf(hv.y, wq[1], acc[j]);
          acc[j] = fmaf(hv.z, wq[2], acc[j]);
          acc[j] = fmaf(hv.w, wq[3], acc[j]);
        }
      }
    }
  }
  if (t < 112) {
#pragma unroll
    for (int j = 0; j < 8; j++)
      out[(size_t)(bs + j) * 784 + n] = 1.f / (1.f + expf(-acc[j]));
  }
}

// ============================= launcher ====================================
extern "C" void kernel_launch(void* const* d_in, const int* in_sizes, int n_in,
                              void* d_out, int out_size, void* d_ws, size_t ws_size,
                              hipStream_t stream) {
  const float* x   = (const float*)d_in[0];
  const float* c1w = (const float*)d_in[1];
  const float* c1b = (const float*)d_in[2];
  const float* pw  = (const float*)d_in[3];
  const float* pb  = (const float*)d_in[4];
  const float* rw  = (const float*)d_in[5];
  const float* w1  = (const float*)d_in[6];
  const float* b1  = (const float*)d_in[7];
  const float* w2  = (const float*)d_in[8];
  const float* b2  = (const float*)d_in[9];
  const float* w3  = (const float*)d_in[10];
  const float* b3  = (const float*)d_in[11];
  float* out = (float*)d_out;
  float* ws = (float*)d_ws;

  // wGp padded by one extra step (18432 B) for the K-loop W prefetch overrun
  const size_t WGP_F = ((size_t)672 * 4 * 4608 + 18432) / 4;
  const size_t U_F = 2359296;
  const size_t SMALL_F = 40960 + 4096 + 256 + 131072 + 262144;
  const size_t fixed_f = WGP_F + 2 * PQ_F + U_F + SMALL_F;
  int chunk = 256;
  while (chunk > 8 && (fixed_f + (size_t)chunk * 104960) * 4 > ws_size) chunk >>= 1;

  __hip_bfloat16* wGp  = (__hip_bfloat16*)ws;
  __hip_bfloat16* hTgc = (__hip_bfloat16*)(ws + WGP_F);
  float* pq   = ws + WGP_F + (size_t)chunk * 104960;   // 2 partial buffers
  float* u    = pq + 2 * PQ_F;
  float* vecs = u + U_F;
  float* sel  = vecs + 40960;
  int*   amv  = (int*)(sel + 4096);
  float* h1   = sel + 4096 + 256;
  float* h2   = h1 + 131072;

  k_wrep<<<dim3(2688), dim3(256), 0, stream>>>(pw, wGp);
  for (int c0 = 0; c0 < 256; c0 += chunk) {
    k_conv1<<<dim3(chunk * 4), dim3(256), 0, stream>>>(x + (size_t)c0 * 784, c1w, c1b, hTgc);
    k_conv2<<<dim3((chunk / 4) * 8), dim3(512), 0, stream>>>(hTgc, wGp, pq, c0);
  }
  k_squash<<<dim3(1152), dim3(256), 0, stream>>>(pq, pb, u);
  k_route<<<dim3(2560), dim3(256), 0, stream>>>(u, rw, vecs);
  k_cls<<<dim3(4), dim3(64), 0, stream>>>(vecs, out, sel, amv);
  k_dec1<<<dim3(256), dim3(512), 0, stream>>>(sel, amv, w1, b1, h1);
  k_dec2<<<dim3(256), dim3(128), 0, stream>>>(h1, w2, b2, h2);
  k_dec3<<<dim3(224), dim3(128), 0, stream>>>(h2, w3, b3, out + 2560);
}